// Round 3
// baseline (983.497 us; speedup 1.0000x reference)
//
#include <hip/hip_runtime.h>
#include <hip/hip_bf16.h>
#include <cstddef>

#define D_MODELc 256
#define D_STATEc 16
#define D_INNERc 512
#define DT_RANKc 16
#define BATCHc   4
#define SEQLENc  4096
#define NCHUNK   64
#define CHUNK    64                   // NCHUNK*CHUNK == SEQLEN

__device__ __forceinline__ float siluf(float v) {
    return v / (1.f + __expf(-v));
}

// ---------------------------------------------------------------------------
// NT GEMM: C[m,n] = sum_k A[m,k] * B[n,k].
// A:(M x K) row-major with row stride lda; B:(N x K) row-major, row stride ldb.
// EPI==0: out0[m*N+n]  = v
// EPI==1: silu split (N must be 1024): n<512 -> out0[m*512+n]=silu(v)
//                                      else  -> out1[m*512+n-512]=silu(v)
// EPI==2: out0[m*N+n] += v
// Tiles: 64x64, BK=32, 256 threads, 4x4 per thread. Requires K%32==0,
// lda%4==0, ldb%4==0 (16B-aligned float4 loads).
// ---------------------------------------------------------------------------
template<int EPI>
__global__ __launch_bounds__(256) void gemm_nt(const float* __restrict__ A, int lda,
                                               const float* __restrict__ B, int ldb,
                                               float* __restrict__ out0,
                                               float* __restrict__ out1,
                                               int M, int N, int K) {
    __shared__ float As[32][65];
    __shared__ float Bs[32][65];
    const int m0 = blockIdx.y * 64;
    const int n0 = blockIdx.x * 64;
    const int t  = threadIdx.x;
    const int tx = t & 15, ty = t >> 4;
    float acc[4][4] = {};
    for (int k0 = 0; k0 < K; k0 += 32) {
        #pragma unroll
        for (int i = 0; i < 2; i++) {
            int li = t + i * 256;            // 0..511 float4 slots
            int row = li >> 3, c4 = li & 7;  // 8 float4 per 32-wide k-row
            float4 v = *(const float4*)&A[(size_t)(m0 + row) * lda + k0 + c4 * 4];
            As[c4*4+0][row] = v.x; As[c4*4+1][row] = v.y;
            As[c4*4+2][row] = v.z; As[c4*4+3][row] = v.w;
        }
        #pragma unroll
        for (int i = 0; i < 2; i++) {
            int li = t + i * 256;
            int row = li >> 3, c4 = li & 7;
            float4 v = *(const float4*)&B[(size_t)(n0 + row) * ldb + k0 + c4 * 4];
            Bs[c4*4+0][row] = v.x; Bs[c4*4+1][row] = v.y;
            Bs[c4*4+2][row] = v.z; Bs[c4*4+3][row] = v.w;
        }
        __syncthreads();
        #pragma unroll
        for (int kk = 0; kk < 32; kk++) {
            float a[4], b[4];
            #pragma unroll
            for (int i = 0; i < 4; i++) { a[i] = As[kk][ty*4+i]; b[i] = Bs[kk][tx*4+i]; }
            #pragma unroll
            for (int i = 0; i < 4; i++)
                #pragma unroll
                for (int j = 0; j < 4; j++) acc[i][j] += a[i] * b[j];
        }
        __syncthreads();
    }
    #pragma unroll
    for (int i = 0; i < 4; i++) {
        int m = m0 + ty*4 + i;
        #pragma unroll
        for (int j = 0; j < 4; j++) {
            int n = n0 + tx*4 + j;
            float v = acc[i][j];
            if (EPI == 0) {
                out0[(size_t)m * N + n] = v;
            } else if (EPI == 2) {
                out0[(size_t)m * N + n] += v;
            } else {
                float s = siluf(v);
                if (n < 512) out0[(size_t)m * 512 + n] = s;
                else         out1[(size_t)m * 512 + (n - 512)] = s;
            }
        }
    }
}

// ---------------------------------------------------------------------------
// x_dbl = u @ Wx.T : (M,512) x (48,512) -> (M,48)
// ---------------------------------------------------------------------------
__global__ __launch_bounds__(256) void xdbl_kernel(const float* __restrict__ U,
                                                   const float* __restrict__ Wx,
                                                   float* __restrict__ out) {
    __shared__ float Us[64][65];
    __shared__ float Ws[48][65];
    const int m0 = blockIdx.x * 64;
    const int t  = threadIdx.x;
    const int mt = t >> 2;
    const int jb = (t & 3) * 12;
    float acc[12] = {};
    for (int k0 = 0; k0 < 512; k0 += 64) {
        #pragma unroll
        for (int i = 0; i < 4; i++) {
            int li = t + i * 256;            // 0..1023, 16 float4 per row
            int row = li >> 4, c4 = li & 15;
            float4 v = *(const float4*)&U[(size_t)(m0 + row) * 512 + k0 + c4 * 4];
            Us[row][c4*4+0] = v.x; Us[row][c4*4+1] = v.y;
            Us[row][c4*4+2] = v.z; Us[row][c4*4+3] = v.w;
        }
        #pragma unroll
        for (int i = 0; i < 3; i++) {
            int li = t + i * 256;            // 0..767
            int row = li >> 4, c4 = li & 15;
            float4 v = *(const float4*)&Wx[(size_t)row * 512 + k0 + c4 * 4];
            Ws[row][c4*4+0] = v.x; Ws[row][c4*4+1] = v.y;
            Ws[row][c4*4+2] = v.z; Ws[row][c4*4+3] = v.w;
        }
        __syncthreads();
        for (int kk = 0; kk < 64; kk++) {
            float a = Us[mt][kk];
            #pragma unroll
            for (int j = 0; j < 12; j++) acc[j] += a * Ws[jb + j][kk];
        }
        __syncthreads();
    }
    #pragma unroll
    for (int j = 0; j < 12; j++)
        out[(size_t)(m0 + mt) * 48 + jb + j] = acc[j];
}

// ---------------------------------------------------------------------------
// Chunked scan, one direction, PB batches.
// delta recomputed inline: softplus(xd[:, :16] @ Wdt[d] + bdt[d]).
// P/S layout: [b][chunk][n][d], d fastest (512).
// ---------------------------------------------------------------------------
__global__ __launch_bounds__(256) void scan_phaseA(
        const float* __restrict__ U, const float* __restrict__ XD,
        const float* __restrict__ Wdt, const float* __restrict__ bdt,
        const float* __restrict__ AL,
        float* __restrict__ P, float* __restrict__ S, int dir) {
    const int c = blockIdx.x;
    const int d = blockIdx.y * 256 + threadIdx.x;
    const int b = blockIdx.z;
    float w[16], a[16], s[16], p[16];
    #pragma unroll
    for (int n = 0; n < 16; n++) {
        w[n] = Wdt[d * 16 + n];
        a[n] = -__expf(AL[d * 16 + n]);
        s[n] = 0.f; p[n] = 1.f;
    }
    const float bb = bdt[d];
    for (int i = 0; i < CHUNK; i++) {
        int tt = c * CHUNK + i;
        int l  = dir ? (SEQLENc - 1 - tt) : tt;
        size_t row = (size_t)b * SEQLENc + l;
        float uu = U[row * 512 + d];
        const float* xr = &XD[row * 48];
        float acc = bb;
        #pragma unroll
        for (int r = 0; r < 16; r++) acc += xr[r] * w[r];
        float dl = (acc > 20.f) ? acc : log1pf(__expf(acc));
        float du = dl * uu;
        #pragma unroll
        for (int n = 0; n < 16; n++) {
            float Bn = xr[16 + n];
            float dA = __expf(dl * a[n]);
            p[n] *= dA;
            s[n] = dA * s[n] + du * Bn;
        }
    }
    size_t base = (((size_t)b * NCHUNK + c) * 16) * 512 + d;
    #pragma unroll
    for (int n = 0; n < 16; n++) {
        P[base + (size_t)n * 512] = p[n];
        S[base + (size_t)n * 512] = s[n];
    }
}

// Serial over chunks; overwrites S with the chunk ENTRY state (E).
__global__ __launch_bounds__(256) void scan_phaseB(const float* __restrict__ P,
                                                   float* __restrict__ S,
                                                   int PB) {
    const int g   = blockIdx.x * 256 + threadIdx.x;  // 0 .. PB*8192-1
    const int d   = g & 511;
    const int n   = (g >> 9) & 15;
    const int b   = g >> 13;
    const size_t stride = (size_t)16 * 512;
    size_t base = (((size_t)b * NCHUNK) * 16 + n) * 512 + d;
    float carry = 0.f;
    for (int c = 0; c < NCHUNK; c++) {
        size_t off = base + (size_t)c * stride;
        float pp = P[off], ss = S[off];
        S[off] = carry;               // entry state for chunk c
        carry = pp * carry + ss;
    }
}

__global__ __launch_bounds__(256) void scan_phaseC(
        const float* __restrict__ U, const float* __restrict__ XD,
        const float* __restrict__ Wdt, const float* __restrict__ bdt,
        const float* __restrict__ AL,
        const float* __restrict__ E,    // = S buffer (entry states)
        const float* __restrict__ SZ,   // silu(z)
        const float* __restrict__ Dp,
        float* __restrict__ Y, int dir) {
    const int c = blockIdx.x;
    const int d = blockIdx.y * 256 + threadIdx.x;
    const int b = blockIdx.z;
    float w[16], a[16], s[16];
    size_t base = (((size_t)b * NCHUNK + c) * 16) * 512 + d;
    #pragma unroll
    for (int n = 0; n < 16; n++) {
        w[n] = Wdt[d * 16 + n];
        a[n] = -__expf(AL[d * 16 + n]);
        s[n] = E[base + (size_t)n * 512];
    }
    const float bb = bdt[d];
    const float Dd = Dp[d];
    for (int i = 0; i < CHUNK; i++) {
        int tt = c * CHUNK + i;
        int l  = dir ? (SEQLENc - 1 - tt) : tt;
        size_t row = (size_t)b * SEQLENc + l;
        float uu = U[row * 512 + d];
        const float* xr = &XD[row * 48];
        float acc = bb;
        #pragma unroll
        for (int r = 0; r < 16; r++) acc += xr[r] * w[r];
        float dl = (acc > 20.f) ? acc : log1pf(__expf(acc));
        float du = dl * uu;
        float y = 0.f;
        #pragma unroll
        for (int n = 0; n < 16; n++) {
            float Bn = xr[16 + n];
            float Cn = xr[32 + n];
            float dA = __expf(dl * a[n]);
            s[n] = dA * s[n] + du * Bn;
            y += s[n] * Cn;
        }
        Y[row * 512 + d] = (y + uu * Dd) * SZ[row * 512 + d];
    }
}

// ---------------------------------------------------------------------------
extern "C" void kernel_launch(void* const* d_in, const int* in_sizes, int n_in,
                              void* d_out, int out_size, void* d_ws, size_t ws_size,
                              hipStream_t stream) {
    const float* h    = (const float*)d_in[0];
    const float* Wi_f = (const float*)d_in[1];
    const float* Wi_b = (const float*)d_in[2];
    const float* Wx_f = (const float*)d_in[3];
    const float* Wx_b = (const float*)d_in[4];
    const float* Wdt_f= (const float*)d_in[5];
    const float* Wdt_b= (const float*)d_in[6];
    const float* bdt_f= (const float*)d_in[7];
    const float* bdt_b= (const float*)d_in[8];
    const float* Al_f = (const float*)d_in[9];
    const float* Al_b = (const float*)d_in[10];
    const float* D_f  = (const float*)d_in[11];
    const float* D_b  = (const float*)d_in[12];
    const float* Wo   = (const float*)d_in[13];
    float* out = (float*)d_out;
    float* ws  = (float*)d_ws;

    // per-batch float counts
    const size_t FB = (size_t)SEQLENc * D_INNERc;       // 2,097,152 (u / sz / y)
    const size_t FX = (size_t)SEQLENc * 48;             //   196,608 (xd)
    const size_t FP = (size_t)NCHUNK * 16 * 512;        //   524,288 (P or S)
    const size_t per_b_bytes = (3 * FB + FX + 2 * FP) * sizeof(float);  // ~28.75 MB

    int PB = 4;                                  // batches per pass
    if ((size_t)4 * per_b_bytes > ws_size) PB = 2;
    if ((size_t)2 * per_b_bytes > ws_size) PB = 1;

    float* u  = ws;
    float* sz = u  + (size_t)PB * FB;
    float* y  = sz + (size_t)PB * FB;
    float* xd = y  + (size_t)PB * FB;
    float* P  = xd + (size_t)PB * FX;
    float* S  = P  + (size_t)PB * FP;

    for (int dir = 0; dir < 2; dir++) {
        const float* Wi  = dir ? Wi_b  : Wi_f;
        const float* Wx  = dir ? Wx_b  : Wx_f;
        const float* Wdt = dir ? Wdt_b : Wdt_f;
        const float* bdt = dir ? bdt_b : bdt_f;
        const float* Al  = dir ? Al_b  : Al_f;
        const float* Dp  = dir ? D_b   : D_f;
        for (int b0 = 0; b0 < BATCHc; b0 += PB) {
            const int Mp = PB * SEQLENc;
            const float* hB  = h   + (size_t)b0 * SEQLENc * D_MODELc;
            float*       oB  = out + (size_t)b0 * SEQLENc * D_MODELc;

            gemm_nt<1><<<dim3(1024/64, Mp/64), 256, 0, stream>>>(
                hB, D_MODELc, Wi, D_MODELc, u, sz, Mp, 1024, D_MODELc);

            xdbl_kernel<<<Mp/64, 256, 0, stream>>>(u, Wx, xd);

            scan_phaseA<<<dim3(NCHUNK, 2, PB), 256, 0, stream>>>(
                u, xd, Wdt, bdt, Al, P, S, dir);
            scan_phaseB<<<PB * 32, 256, 0, stream>>>(P, S, PB);
            scan_phaseC<<<dim3(NCHUNK, 2, PB), 256, 0, stream>>>(
                u, xd, Wdt, bdt, Al, S, sz, Dp, y, dir);

            if (dir == 0)
                gemm_nt<0><<<dim3(256/64, Mp/64), 256, 0, stream>>>(
                    y, D_INNERc, Wo, 1024, oB, nullptr, Mp, D_MODELc, D_INNERc);
            else
                gemm_nt<2><<<dim3(256/64, Mp/64), 256, 0, stream>>>(
                    y, D_INNERc, Wo + 512, 1024, oB, nullptr, Mp, D_MODELc, D_INNERc);
        }
    }
}

// Round 4
// 699.986 us; speedup vs baseline: 1.4050x; 1.4050x over previous
//
#include <hip/hip_runtime.h>
#include <hip/hip_bf16.h>
#include <cstddef>
#include <cstdint>

#define D_MODELc 256
#define D_STATEc 16
#define D_INNERc 512
#define DT_RANKc 16
#define BATCHc   4
#define SEQLENc  4096
#define NCHUNK   64
#define CHUNK    64                   // NCHUNK*CHUNK == SEQLEN

typedef unsigned short u16;
typedef __attribute__((ext_vector_type(8))) short bf16x8;   // 8 bf16 (4 VGPR)
typedef __attribute__((ext_vector_type(4))) float f32x4;    // 4 f32 acc

__device__ __forceinline__ float siluf(float v) { return v / (1.f + __expf(-v)); }

__device__ __forceinline__ u16 bf16_rne(float f) {
    uint32_t u = __float_as_uint(f);
    u += 0x7fffu + ((u >> 16) & 1u);
    return (u16)(u >> 16);
}
__device__ __forceinline__ float bf16_to_f(u16 h) {
    return __uint_as_float(((uint32_t)h) << 16);
}

// global->LDS direct copy, 16B per lane; LDS dest = wave-uniform base + lane*16
#define GLL16(g, l) __builtin_amdgcn_global_load_lds( \
    (const __attribute__((address_space(1))) uint32_t*)(g), \
    (__attribute__((address_space(3))) uint32_t*)(l), 16, 0, 0)

// ---------------------------------------------------------------------------
// split f32 -> (hi, lo) bf16 pair, vectorized x4
// ---------------------------------------------------------------------------
__global__ __launch_bounds__(256) void split_kernel(const float* __restrict__ in,
                                                    u16* __restrict__ hi,
                                                    u16* __restrict__ lo, int n4) {
    int i = blockIdx.x * 256 + threadIdx.x;
    const int stride = gridDim.x * 256;
    for (; i < n4; i += stride) {
        float4 v = ((const float4*)in)[i];
        u16 h0 = bf16_rne(v.x), h1 = bf16_rne(v.y), h2 = bf16_rne(v.z), h3 = bf16_rne(v.w);
        ushort4 hv; hv.x = h0; hv.y = h1; hv.z = h2; hv.w = h3;
        ushort4 lv;
        lv.x = bf16_rne(v.x - bf16_to_f(h0));
        lv.y = bf16_rne(v.y - bf16_to_f(h1));
        lv.z = bf16_rne(v.z - bf16_to_f(h2));
        lv.w = bf16_rne(v.w - bf16_to_f(h3));
        ((ushort4*)hi)[i] = hv;
        ((ushort4*)lo)[i] = lv;
    }
}

// ---------------------------------------------------------------------------
// Split-bf16 MFMA NT GEMM: C[m,n] = sum_k A[m,k]*B[n,k], A=Ah+Al, B=Bh+Bl,
// C ~= Ah*Bh + Ah*Bl + Al*Bh   (3 MFMA per fragment, f32 accumulate)
// Tile 128x128, BK=32, 256 threads = 4 waves (each 64x64).
// LDS: [tile(Ah,Al,Bh,Bl)][kg 0..3][row 0..127][8 bf16]  (32 KB)
// EPI==0: out0[m*N+n]  = v
// EPI==1: N==1024; n<512 -> out0[m*512+n]=silu(v) ; else out1[m*512+n-512]=silu(v)
// EPI==2: out0[m*N+n] += v
// Requires M%128==0, N%128==0, K%32==0.
// ---------------------------------------------------------------------------
template<int EPI>
__global__ __launch_bounds__(256) void gemm_mfma(
        const u16* __restrict__ Ah, const u16* __restrict__ Al, int lda,
        const u16* __restrict__ Bh, const u16* __restrict__ Bl, int ldb,
        float* __restrict__ out0, float* __restrict__ out1,
        int M, int N, int K) {
    __shared__ u16 lds[4][4][128][8];
    const int t    = threadIdx.x;
    const int lane = t & 63;
    const int wid  = t >> 6;
    const int wrow = wid >> 1, wcol = wid & 1;
    const int m0 = blockIdx.y * 128, n0 = blockIdx.x * 128;
    const int lr  = lane & 15;       // frag row/col within 16
    const int kgl = lane >> 4;       // k-group 0..3

    f32x4 acc[4][4] = {};

    for (int k0 = 0; k0 < K; k0 += 32) {
        // ---- stage 4 tiles (Ah,Al,Bh,Bl), 2048 x 16B chunks, 8 per thread
        #pragma unroll
        for (int i = 0; i < 8; i++) {
            int c    = i * 256 + t;          // chunk id
            int tile = c >> 9;               // 0..3 (uniform per wave-issue)
            int kg   = (c >> 7) & 3;
            int row  = c & 127;
            const u16* bsrc = (tile == 0) ? Ah : (tile == 1) ? Al : (tile == 2) ? Bh : Bl;
            int r0 = (tile < 2) ? m0 : n0;
            int ld = (tile < 2) ? lda : ldb;
            const u16* g = bsrc + (size_t)(r0 + row) * ld + k0 + kg * 8;
            GLL16(g, ((char*)lds) + (size_t)c * 16);
        }
        __syncthreads();

        // ---- fragments + MFMA
        bf16x8 afh[4], afl[4];
        #pragma unroll
        for (int mi = 0; mi < 4; mi++) {
            afh[mi] = *(const bf16x8*)&lds[0][kgl][wrow * 64 + mi * 16 + lr][0];
            afl[mi] = *(const bf16x8*)&lds[1][kgl][wrow * 64 + mi * 16 + lr][0];
        }
        #pragma unroll
        for (int ni = 0; ni < 4; ni++) {
            bf16x8 bfh = *(const bf16x8*)&lds[2][kgl][wcol * 64 + ni * 16 + lr][0];
            bf16x8 bfl = *(const bf16x8*)&lds[3][kgl][wcol * 64 + ni * 16 + lr][0];
            #pragma unroll
            for (int mi = 0; mi < 4; mi++) {
                acc[mi][ni] = __builtin_amdgcn_mfma_f32_16x16x32_bf16(afh[mi], bfh, acc[mi][ni], 0, 0, 0);
                acc[mi][ni] = __builtin_amdgcn_mfma_f32_16x16x32_bf16(afh[mi], bfl, acc[mi][ni], 0, 0, 0);
                acc[mi][ni] = __builtin_amdgcn_mfma_f32_16x16x32_bf16(afl[mi], bfh, acc[mi][ni], 0, 0, 0);
            }
        }
        __syncthreads();
    }

    // ---- epilogue: C/D map col=lane&15, row=(lane>>4)*4+reg  [m89/m91]
    #pragma unroll
    for (int mi = 0; mi < 4; mi++) {
        #pragma unroll
        for (int ni = 0; ni < 4; ni++) {
            #pragma unroll
            for (int r = 0; r < 4; r++) {
                int m = m0 + wrow * 64 + mi * 16 + kgl * 4 + r;
                int n = n0 + wcol * 64 + ni * 16 + lr;
                float v = acc[mi][ni][r];
                if (EPI == 0) {
                    out0[(size_t)m * N + n] = v;
                } else if (EPI == 2) {
                    out0[(size_t)m * N + n] += v;
                } else {
                    float s = siluf(v);
                    if (n < 512) out0[(size_t)m * 512 + n] = s;
                    else         out1[(size_t)m * 512 + (n - 512)] = s;
                }
            }
        }
    }
}

// ---------------------------------------------------------------------------
// x_dbl = u @ Wx.T : (M,512) x (48,512) -> (M,48)   (f32 VALU)
// ---------------------------------------------------------------------------
__global__ __launch_bounds__(256) void xdbl_kernel(const float* __restrict__ U,
                                                   const float* __restrict__ Wx,
                                                   float* __restrict__ out) {
    __shared__ float Us[64][65];
    __shared__ float Ws[48][65];
    const int m0 = blockIdx.x * 64;
    const int t  = threadIdx.x;
    const int mt = t >> 2;
    const int jb = (t & 3) * 12;
    float acc[12] = {};
    for (int k0 = 0; k0 < 512; k0 += 64) {
        #pragma unroll
        for (int i = 0; i < 4; i++) {
            int li = t + i * 256;
            int row = li >> 4, c4 = li & 15;
            float4 v = *(const float4*)&U[(size_t)(m0 + row) * 512 + k0 + c4 * 4];
            Us[row][c4*4+0] = v.x; Us[row][c4*4+1] = v.y;
            Us[row][c4*4+2] = v.z; Us[row][c4*4+3] = v.w;
        }
        #pragma unroll
        for (int i = 0; i < 3; i++) {
            int li = t + i * 256;
            int row = li >> 4, c4 = li & 15;
            float4 v = *(const float4*)&Wx[(size_t)row * 512 + k0 + c4 * 4];
            Ws[row][c4*4+0] = v.x; Ws[row][c4*4+1] = v.y;
            Ws[row][c4*4+2] = v.z; Ws[row][c4*4+3] = v.w;
        }
        __syncthreads();
        for (int kk = 0; kk < 64; kk++) {
            float a = Us[mt][kk];
            #pragma unroll
            for (int j = 0; j < 12; j++) acc[j] += a * Ws[jb + j][kk];
        }
        __syncthreads();
    }
    #pragma unroll
    for (int j = 0; j < 12; j++)
        out[(size_t)(m0 + mt) * 48 + jb + j] = acc[j];
}

// ---------------------------------------------------------------------------
// Chunked scan (delta recomputed inline). P/S layout: [b][chunk][n][d].
// ---------------------------------------------------------------------------
__global__ __launch_bounds__(256) void scan_phaseA(
        const float* __restrict__ U, const float* __restrict__ XD,
        const float* __restrict__ Wdt, const float* __restrict__ bdt,
        const float* __restrict__ AL,
        float* __restrict__ P, float* __restrict__ S, int dir) {
    const int c = blockIdx.x;
    const int d = blockIdx.y * 256 + threadIdx.x;
    const int b = blockIdx.z;
    float w[16], a[16], s[16], p[16];
    #pragma unroll
    for (int n = 0; n < 16; n++) {
        w[n] = Wdt[d * 16 + n];
        a[n] = -__expf(AL[d * 16 + n]);
        s[n] = 0.f; p[n] = 1.f;
    }
    const float bb = bdt[d];
    for (int i = 0; i < CHUNK; i++) {
        int tt = c * CHUNK + i;
        int l  = dir ? (SEQLENc - 1 - tt) : tt;
        size_t row = (size_t)b * SEQLENc + l;
        float uu = U[row * 512 + d];
        const float* xr = &XD[row * 48];
        float acc = bb;
        #pragma unroll
        for (int r = 0; r < 16; r++) acc += xr[r] * w[r];
        float dl = (acc > 20.f) ? acc : log1pf(__expf(acc));
        float du = dl * uu;
        #pragma unroll
        for (int n = 0; n < 16; n++) {
            float Bn = xr[16 + n];
            float dA = __expf(dl * a[n]);
            p[n] *= dA;
            s[n] = dA * s[n] + du * Bn;
        }
    }
    size_t base = (((size_t)b * NCHUNK + c) * 16) * 512 + d;
    #pragma unroll
    for (int n = 0; n < 16; n++) {
        P[base + (size_t)n * 512] = p[n];
        S[base + (size_t)n * 512] = s[n];
    }
}

__global__ __launch_bounds__(256) void scan_phaseB(const float* __restrict__ P,
                                                   float* __restrict__ S) {
    const int g   = blockIdx.x * 256 + threadIdx.x;
    const int d   = g & 511;
    const int n   = (g >> 9) & 15;
    const int b   = g >> 13;
    const size_t stride = (size_t)16 * 512;
    size_t base = (((size_t)b * NCHUNK) * 16 + n) * 512 + d;
    float carry = 0.f;
    for (int c = 0; c < NCHUNK; c++) {
        size_t off = base + (size_t)c * stride;
        float pp = P[off], ss = S[off];
        S[off] = carry;               // entry state for chunk c
        carry = pp * carry + ss;
    }
}

__global__ __launch_bounds__(256) void scan_phaseC(
        const float* __restrict__ U, const float* __restrict__ XD,
        const float* __restrict__ Wdt, const float* __restrict__ bdt,
        const float* __restrict__ AL,
        const float* __restrict__ E,    // entry states (in S buffer)
        const float* __restrict__ SZ,   // silu(z)
        const float* __restrict__ Dp,
        u16* __restrict__ Yh, u16* __restrict__ Yl, int dir) {
    const int c = blockIdx.x;
    const int d = blockIdx.y * 256 + threadIdx.x;
    const int b = blockIdx.z;
    float w[16], a[16], s[16];
    size_t base = (((size_t)b * NCHUNK + c) * 16) * 512 + d;
    #pragma unroll
    for (int n = 0; n < 16; n++) {
        w[n] = Wdt[d * 16 + n];
        a[n] = -__expf(AL[d * 16 + n]);
        s[n] = E[base + (size_t)n * 512];
    }
    const float bb = bdt[d];
    const float Dd = Dp[d];
    for (int i = 0; i < CHUNK; i++) {
        int tt = c * CHUNK + i;
        int l  = dir ? (SEQLENc - 1 - tt) : tt;
        size_t row = (size_t)b * SEQLENc + l;
        float uu = U[row * 512 + d];
        const float* xr = &XD[row * 48];
        float acc = bb;
        #pragma unroll
        for (int r = 0; r < 16; r++) acc += xr[r] * w[r];
        float dl = (acc > 20.f) ? acc : log1pf(__expf(acc));
        float du = dl * uu;
        float y = 0.f;
        #pragma unroll
        for (int n = 0; n < 16; n++) {
            float Bn = xr[16 + n];
            float Cn = xr[32 + n];
            float dA = __expf(dl * a[n]);
            s[n] = dA * s[n] + du * Bn;
            y += s[n] * Cn;
        }
        float yv = (y + uu * Dd) * SZ[row * 512 + d];
        u16 yh = bf16_rne(yv);
        Yh[row * 512 + d] = yh;
        Yl[row * 512 + d] = bf16_rne(yv - bf16_to_f(yh));
    }
}

// ---------------------------------------------------------------------------
extern "C" void kernel_launch(void* const* d_in, const int* in_sizes, int n_in,
                              void* d_out, int out_size, void* d_ws, size_t ws_size,
                              hipStream_t stream) {
    const float* h    = (const float*)d_in[0];
    const float* Wi_f = (const float*)d_in[1];
    const float* Wi_b = (const float*)d_in[2];
    const float* Wx_f = (const float*)d_in[3];
    const float* Wx_b = (const float*)d_in[4];
    const float* Wdt_f= (const float*)d_in[5];
    const float* Wdt_b= (const float*)d_in[6];
    const float* bdt_f= (const float*)d_in[7];
    const float* bdt_b= (const float*)d_in[8];
    const float* Al_f = (const float*)d_in[9];
    const float* Al_b = (const float*)d_in[10];
    const float* D_f  = (const float*)d_in[11];
    const float* D_b  = (const float*)d_in[12];
    const float* Wo   = (const float*)d_in[13];
    float* out = (float*)d_out;

    // ---- workspace layout --------------------------------------------------
    const size_t W_ELE = 1024 * 256;                 // Wi (per dir) / Wo elements
    const size_t FB   = (size_t)SEQLENc * D_INNERc;  // per-batch 512-wide
    const size_t FH   = (size_t)SEQLENc * D_MODELc;  // per-batch 256-wide
    const size_t FX   = (size_t)SEQLENc * 48;
    const size_t FP   = (size_t)NCHUNK * 16 * 512;

    const size_t fixed_bytes = 6 * W_ELE * sizeof(u16);           // Wi hi/lo x2 dirs + Wo hi/lo
    const size_t per_b = 2 * FH * sizeof(u16)                     // h hi/lo
                       + 2 * FB * sizeof(float)                   // u, sz
                       + FX * sizeof(float)                       // xd
                       + 2 * FP * sizeof(float)                   // P, S
                       + 2 * FB * sizeof(u16);                    // y hi/lo
    int PB = 4;
    if (fixed_bytes + 4 * per_b + 4096 > ws_size) PB = 2;
    if (fixed_bytes + 2 * per_b + 4096 > ws_size) PB = 1;

    char* cur = (char*)d_ws;
    auto alloc = [&](size_t bytes) -> char* {
        char* p = cur; cur += (bytes + 255) & ~(size_t)255; return p;
    };
    u16* WiH[2]; u16* WiL[2];
    WiH[0] = (u16*)alloc(W_ELE * 2); WiL[0] = (u16*)alloc(W_ELE * 2);
    WiH[1] = (u16*)alloc(W_ELE * 2); WiL[1] = (u16*)alloc(W_ELE * 2);
    u16* WoH = (u16*)alloc(W_ELE * 2); u16* WoL = (u16*)alloc(W_ELE * 2);
    u16*   hH = (u16*)alloc((size_t)PB * FH * 2);
    u16*   hL = (u16*)alloc((size_t)PB * FH * 2);
    float* u  = (float*)alloc((size_t)PB * FB * 4);
    float* sz = (float*)alloc((size_t)PB * FB * 4);
    float* xd = (float*)alloc((size_t)PB * FX * 4);
    float* P  = (float*)alloc((size_t)PB * FP * 4);
    float* S  = (float*)alloc((size_t)PB * FP * 4);
    u16*   yH = (u16*)alloc((size_t)PB * FB * 2);
    u16*   yL = (u16*)alloc((size_t)PB * FB * 2);

    // ---- pre-split weights (once) -----------------------------------------
    {
        int n4 = (int)(W_ELE / 4);
        int blocks = (n4 + 255) / 256; if (blocks > 1024) blocks = 1024;
        split_kernel<<<blocks, 256, 0, stream>>>(Wi_f, WiH[0], WiL[0], n4);
        split_kernel<<<blocks, 256, 0, stream>>>(Wi_b, WiH[1], WiL[1], n4);
        split_kernel<<<blocks, 256, 0, stream>>>(Wo,   WoH,    WoL,    n4);
    }

    for (int b0 = 0; b0 < BATCHc; b0 += PB) {
        const int Mp = PB * SEQLENc;
        const float* hB = h   + (size_t)b0 * FH;
        float*       oB = out + (size_t)b0 * FH;

        {   // split h for this batch group (used by both dirs)
            int n4 = (int)((size_t)PB * FH / 4);
            int blocks = (n4 + 255) / 256; if (blocks > 2048) blocks = 2048;
            split_kernel<<<blocks, 256, 0, stream>>>(hB, hH, hL, n4);
        }

        for (int dir = 0; dir < 2; dir++) {
            const float* Wx  = dir ? Wx_b  : Wx_f;
            const float* Wdt = dir ? Wdt_b : Wdt_f;
            const float* bdt = dir ? bdt_b : bdt_f;
            const float* Al  = dir ? Al_b  : Al_f;
            const float* Dp  = dir ? D_b   : D_f;

            // in-projection + silu epilogue -> u, sz
            gemm_mfma<1><<<dim3(1024 / 128, Mp / 128), 256, 0, stream>>>(
                hH, hL, D_MODELc, WiH[dir], WiL[dir], D_MODELc,
                u, sz, Mp, 1024, D_MODELc);

            xdbl_kernel<<<Mp / 64, 256, 0, stream>>>(u, Wx, xd);

            scan_phaseA<<<dim3(NCHUNK, 2, PB), 256, 0, stream>>>(
                u, xd, Wdt, bdt, Al, P, S, dir);
            scan_phaseB<<<PB * 32, 256, 0, stream>>>(P, S);
            scan_phaseC<<<dim3(NCHUNK, 2, PB), 256, 0, stream>>>(
                u, xd, Wdt, bdt, Al, S, sz, Dp, yH, yL, dir);

            // out-projection (dir0 store, dir1 accumulate)
            if (dir == 0)
                gemm_mfma<0><<<dim3(256 / 128, Mp / 128), 256, 0, stream>>>(
                    yH, yL, D_INNERc, WoH, WoL, 1024,
                    oB, nullptr, Mp, D_MODELc, D_INNERc);
            else
                gemm_mfma<2><<<dim3(256 / 128, Mp / 128), 256, 0, stream>>>(
                    yH, yL, D_INNERc, WoH + 512, WoL + 512, 1024,
                    oB, nullptr, Mp, D_MODELc, D_INNERc);
        }
    }
}

// Round 5
// 521.935 us; speedup vs baseline: 1.8843x; 1.3411x over previous
//
#include <hip/hip_runtime.h>
#include <hip/hip_bf16.h>
#include <cstddef>
#include <cstdint>

#define D_MODELc 256
#define D_STATEc 16
#define D_INNERc 512
#define DT_RANKc 16
#define BATCHc   4
#define SEQLENc  4096
#define NCHUNK   128
#define CHUNK    32                   // NCHUNK*CHUNK == SEQLEN

typedef unsigned short u16;
typedef __attribute__((ext_vector_type(8))) short bf16x8;   // 8 bf16 (4 VGPR)
typedef __attribute__((ext_vector_type(4))) float f32x4;    // 4 f32 acc

__device__ __forceinline__ float siluf(float v) { return v / (1.f + __expf(-v)); }

__device__ __forceinline__ u16 bf16_rne(float f) {
    uint32_t u = __float_as_uint(f);
    u += 0x7fffu + ((u >> 16) & 1u);
    return (u16)(u >> 16);
}
__device__ __forceinline__ float bf16_to_f(u16 h) {
    return __uint_as_float(((uint32_t)h) << 16);
}
// softplus, branchless, fast-math
__device__ __forceinline__ float softplusf(float x) {
    return fmaxf(x, 0.f) + __logf(1.f + __expf(-fabsf(x)));
}

// global->LDS direct copy, 16B per lane; LDS dest = wave-uniform base + lane*16
#define GLL16(g, l) __builtin_amdgcn_global_load_lds( \
    (const __attribute__((address_space(1))) uint32_t*)(g), \
    (__attribute__((address_space(3))) uint32_t*)(l), 16, 0, 0)

// ---------------------------------------------------------------------------
// split f32 -> (hi, lo) bf16 pair, vectorized x4
// ---------------------------------------------------------------------------
__global__ __launch_bounds__(256) void split_kernel(const float* __restrict__ in,
                                                    u16* __restrict__ hi,
                                                    u16* __restrict__ lo, int n4) {
    int i = blockIdx.x * 256 + threadIdx.x;
    const int stride = gridDim.x * 256;
    for (; i < n4; i += stride) {
        float4 v = ((const float4*)in)[i];
        u16 h0 = bf16_rne(v.x), h1 = bf16_rne(v.y), h2 = bf16_rne(v.z), h3 = bf16_rne(v.w);
        ushort4 hv; hv.x = h0; hv.y = h1; hv.z = h2; hv.w = h3;
        ushort4 lv;
        lv.x = bf16_rne(v.x - bf16_to_f(h0));
        lv.y = bf16_rne(v.y - bf16_to_f(h1));
        lv.z = bf16_rne(v.z - bf16_to_f(h2));
        lv.w = bf16_rne(v.w - bf16_to_f(h3));
        ((ushort4*)hi)[i] = hv;
        ((ushort4*)lo)[i] = lv;
    }
}

// ---------------------------------------------------------------------------
// Split-bf16 MFMA NT GEMM (see round 4 notes). Tile 128x128, BK=32, 4 waves.
// ---------------------------------------------------------------------------
template<int EPI>
__global__ __launch_bounds__(256) void gemm_mfma(
        const u16* __restrict__ Ah, const u16* __restrict__ Al, int lda,
        const u16* __restrict__ Bh, const u16* __restrict__ Bl, int ldb,
        float* __restrict__ out0, float* __restrict__ out1,
        int M, int N, int K) {
    __shared__ u16 lds[4][4][128][8];
    const int t    = threadIdx.x;
    const int lane = t & 63;
    const int wid  = t >> 6;
    const int wrow = wid >> 1, wcol = wid & 1;
    const int m0 = blockIdx.y * 128, n0 = blockIdx.x * 128;
    const int lr  = lane & 15;       // frag row/col within 16
    const int kgl = lane >> 4;       // k-group 0..3

    f32x4 acc[4][4] = {};

    for (int k0 = 0; k0 < K; k0 += 32) {
        #pragma unroll
        for (int i = 0; i < 8; i++) {
            int c    = i * 256 + t;          // chunk id
            int tile = c >> 9;               // 0..3
            int kg   = (c >> 7) & 3;
            int row  = c & 127;
            const u16* bsrc = (tile == 0) ? Ah : (tile == 1) ? Al : (tile == 2) ? Bh : Bl;
            int r0 = (tile < 2) ? m0 : n0;
            int ld = (tile < 2) ? lda : ldb;
            const u16* g = bsrc + (size_t)(r0 + row) * ld + k0 + kg * 8;
            GLL16(g, ((char*)lds) + (size_t)c * 16);
        }
        __syncthreads();

        bf16x8 afh[4], afl[4];
        #pragma unroll
        for (int mi = 0; mi < 4; mi++) {
            afh[mi] = *(const bf16x8*)&lds[0][kgl][wrow * 64 + mi * 16 + lr][0];
            afl[mi] = *(const bf16x8*)&lds[1][kgl][wrow * 64 + mi * 16 + lr][0];
        }
        #pragma unroll
        for (int ni = 0; ni < 4; ni++) {
            bf16x8 bfh = *(const bf16x8*)&lds[2][kgl][wcol * 64 + ni * 16 + lr][0];
            bf16x8 bfl = *(const bf16x8*)&lds[3][kgl][wcol * 64 + ni * 16 + lr][0];
            #pragma unroll
            for (int mi = 0; mi < 4; mi++) {
                acc[mi][ni] = __builtin_amdgcn_mfma_f32_16x16x32_bf16(afh[mi], bfh, acc[mi][ni], 0, 0, 0);
                acc[mi][ni] = __builtin_amdgcn_mfma_f32_16x16x32_bf16(afh[mi], bfl, acc[mi][ni], 0, 0, 0);
                acc[mi][ni] = __builtin_amdgcn_mfma_f32_16x16x32_bf16(afl[mi], bfh, acc[mi][ni], 0, 0, 0);
            }
        }
        __syncthreads();
    }

    // epilogue: C/D map col=lane&15, row=(lane>>4)*4+reg  [m89/m91]
    #pragma unroll
    for (int mi = 0; mi < 4; mi++) {
        #pragma unroll
        for (int ni = 0; ni < 4; ni++) {
            #pragma unroll
            for (int r = 0; r < 4; r++) {
                int m = m0 + wrow * 64 + mi * 16 + kgl * 4 + r;
                int n = n0 + wcol * 64 + ni * 16 + lr;
                float v = acc[mi][ni][r];
                if (EPI == 0) {
                    out0[(size_t)m * N + n] = v;
                } else if (EPI == 2) {
                    out0[(size_t)m * N + n] += v;
                } else {
                    float s = siluf(v);
                    if (n < 512) out0[(size_t)m * 512 + n] = s;
                    else         out1[(size_t)m * 512 + (n - 512)] = s;
                }
            }
        }
    }
}

// ---------------------------------------------------------------------------
// x_dbl = u @ Wx.T : (M,512) x (48,512) -> (M,48)   (f32 VALU)
// ---------------------------------------------------------------------------
__global__ __launch_bounds__(256) void xdbl_kernel(const float* __restrict__ U,
                                                   const float* __restrict__ Wx,
                                                   float* __restrict__ out) {
    __shared__ float Us[64][65];
    __shared__ float Ws[48][65];
    const int m0 = blockIdx.x * 64;
    const int t  = threadIdx.x;
    const int mt = t >> 2;
    const int jb = (t & 3) * 12;
    float acc[12] = {};
    for (int k0 = 0; k0 < 512; k0 += 64) {
        #pragma unroll
        for (int i = 0; i < 4; i++) {
            int li = t + i * 256;
            int row = li >> 4, c4 = li & 15;
            float4 v = *(const float4*)&U[(size_t)(m0 + row) * 512 + k0 + c4 * 4];
            Us[row][c4*4+0] = v.x; Us[row][c4*4+1] = v.y;
            Us[row][c4*4+2] = v.z; Us[row][c4*4+3] = v.w;
        }
        #pragma unroll
        for (int i = 0; i < 3; i++) {
            int li = t + i * 256;
            int row = li >> 4, c4 = li & 15;
            float4 v = *(const float4*)&Wx[(size_t)row * 512 + k0 + c4 * 4];
            Ws[row][c4*4+0] = v.x; Ws[row][c4*4+1] = v.y;
            Ws[row][c4*4+2] = v.z; Ws[row][c4*4+3] = v.w;
        }
        __syncthreads();
        for (int kk = 0; kk < 64; kk++) {
            float a = Us[mt][kk];
            #pragma unroll
            for (int j = 0; j < 12; j++) acc[j] += a * Ws[jb + j][kk];
        }
        __syncthreads();
    }
    #pragma unroll
    for (int j = 0; j < 12; j++)
        out[(size_t)(m0 + mt) * 48 + jb + j] = acc[j];
}

// ---------------------------------------------------------------------------
// Chunked scan. P/S layout: [b][chunk][n][d], d fastest.
// delta recomputed inline. dA via q-powers when a[n]==(n+1)*a0 (runtime check,
// generic exp fallback). Chunk decay p[n] = exp(a[n]*sum_dl) once per chunk.
// ---------------------------------------------------------------------------
__global__ __launch_bounds__(256) void scan_phaseA(
        const float* __restrict__ U, const float* __restrict__ XD,
        const float* __restrict__ Wdt, const float* __restrict__ bdt,
        const float* __restrict__ AL,
        float* __restrict__ P, float* __restrict__ S, int dir) {
    const int c = blockIdx.x;
    const int d = blockIdx.y * 256 + threadIdx.x;
    const int b = blockIdx.z;
    float w[16], a[16], s[16];
    #pragma unroll
    for (int n = 0; n < 16; n++) {
        w[n] = Wdt[d * 16 + n];
        a[n] = -__expf(AL[d * 16 + n]);
        s[n] = 0.f;
    }
    const float a0 = a[0];
    bool pw = (a0 != 0.f);
    #pragma unroll
    for (int n = 1; n < 16; n++)
        pw = pw && (fabsf(a[n] - (float)(n + 1) * a0) <= 3e-6f * fabsf(a[n]));
    const float bb = bdt[d];
    float sdl = 0.f;

    for (int i = 0; i < CHUNK; i++) {
        int tt = c * CHUNK + i;
        int l  = dir ? (SEQLENc - 1 - tt) : tt;
        size_t row = (size_t)b * SEQLENc + l;
        float uu = U[row * 512 + d];
        const float4* xr4 = (const float4*)&XD[row * 48];
        float acc = bb;
        #pragma unroll
        for (int k = 0; k < 4; k++) {
            float4 xa = xr4[k];
            acc += xa.x*w[k*4+0] + xa.y*w[k*4+1] + xa.z*w[k*4+2] + xa.w*w[k*4+3];
        }
        float dl = softplusf(acc);
        sdl += dl;
        float du = dl * uu;
        if (pw) {
            float q = __expf(a0 * dl);
            float dAn = 1.f;
            #pragma unroll
            for (int g = 0; g < 4; g++) {
                float4 B4 = xr4[4 + g];
                float bx[4] = {B4.x, B4.y, B4.z, B4.w};
                #pragma unroll
                for (int j = 0; j < 4; j++) {
                    int n = g * 4 + j;
                    dAn *= q;
                    s[n] = dAn * s[n] + du * bx[j];
                }
            }
        } else {
            #pragma unroll
            for (int g = 0; g < 4; g++) {
                float4 B4 = xr4[4 + g];
                float bx[4] = {B4.x, B4.y, B4.z, B4.w};
                #pragma unroll
                for (int j = 0; j < 4; j++) {
                    int n = g * 4 + j;
                    float dA = __expf(dl * a[n]);
                    s[n] = dA * s[n] + du * bx[j];
                }
            }
        }
    }
    size_t base = (((size_t)b * NCHUNK + c) * 16) * 512 + d;
    #pragma unroll
    for (int n = 0; n < 16; n++) {
        P[base + (size_t)n * 512] = __expf(a[n] * sdl);
        S[base + (size_t)n * 512] = s[n];
    }
}

// Serial over chunks with 1-deep prefetch; overwrites S with chunk ENTRY state.
__global__ __launch_bounds__(256) void scan_phaseB(const float* __restrict__ P,
                                                   float* __restrict__ S) {
    const int g = blockIdx.x * 256 + threadIdx.x;
    const int d = g & 511;
    const int n = (g >> 9) & 15;
    const int b = g >> 13;
    const size_t stride = (size_t)16 * 512;
    size_t off = (((size_t)b * NCHUNK) * 16 + n) * 512 + d;
    float carry = 0.f;
    float pp = P[off], ss = S[off];
    for (int c = 0; c < NCHUNK; c++) {
        float pn = 0.f, sn = 0.f;
        if (c + 1 < NCHUNK) { pn = P[off + stride]; sn = S[off + stride]; }
        S[off] = carry;
        carry = pp * carry + ss;
        pp = pn; ss = sn;
        off += stride;
    }
}

__global__ __launch_bounds__(256) void scan_phaseC(
        const float* __restrict__ U, const float* __restrict__ XD,
        const float* __restrict__ Wdt, const float* __restrict__ bdt,
        const float* __restrict__ AL,
        const float* __restrict__ E,    // entry states (in S buffer)
        const float* __restrict__ SZ,   // silu(z)
        const float* __restrict__ Dp,
        u16* __restrict__ Yh, u16* __restrict__ Yl, int dir) {
    const int c = blockIdx.x;
    const int d = blockIdx.y * 256 + threadIdx.x;
    const int b = blockIdx.z;
    float w[16], a[16], s[16];
    size_t base = (((size_t)b * NCHUNK + c) * 16) * 512 + d;
    #pragma unroll
    for (int n = 0; n < 16; n++) {
        w[n] = Wdt[d * 16 + n];
        a[n] = -__expf(AL[d * 16 + n]);
        s[n] = E[base + (size_t)n * 512];
    }
    const float a0 = a[0];
    bool pw = (a0 != 0.f);
    #pragma unroll
    for (int n = 1; n < 16; n++)
        pw = pw && (fabsf(a[n] - (float)(n + 1) * a0) <= 3e-6f * fabsf(a[n]));
    const float bb = bdt[d];
    const float Dd = Dp[d];

    for (int i = 0; i < CHUNK; i++) {
        int tt = c * CHUNK + i;
        int l  = dir ? (SEQLENc - 1 - tt) : tt;
        size_t row = (size_t)b * SEQLENc + l;
        float uu = U[row * 512 + d];
        const float4* xr4 = (const float4*)&XD[row * 48];
        float acc = bb;
        #pragma unroll
        for (int k = 0; k < 4; k++) {
            float4 xa = xr4[k];
            acc += xa.x*w[k*4+0] + xa.y*w[k*4+1] + xa.z*w[k*4+2] + xa.w*w[k*4+3];
        }
        float dl = softplusf(acc);
        float du = dl * uu;
        float y = 0.f;
        if (pw) {
            float q = __expf(a0 * dl);
            float dAn = 1.f;
            #pragma unroll
            for (int g = 0; g < 4; g++) {
                float4 B4 = xr4[4 + g];
                float4 C4 = xr4[8 + g];
                float bx[4] = {B4.x, B4.y, B4.z, B4.w};
                float cx[4] = {C4.x, C4.y, C4.z, C4.w};
                #pragma unroll
                for (int j = 0; j < 4; j++) {
                    int n = g * 4 + j;
                    dAn *= q;
                    s[n] = dAn * s[n] + du * bx[j];
                    y += s[n] * cx[j];
                }
            }
        } else {
            #pragma unroll
            for (int g = 0; g < 4; g++) {
                float4 B4 = xr4[4 + g];
                float4 C4 = xr4[8 + g];
                float bx[4] = {B4.x, B4.y, B4.z, B4.w};
                float cx[4] = {C4.x, C4.y, C4.z, C4.w};
                #pragma unroll
                for (int j = 0; j < 4; j++) {
                    int n = g * 4 + j;
                    float dA = __expf(dl * a[n]);
                    s[n] = dA * s[n] + du * bx[j];
                    y += s[n] * cx[j];
                }
            }
        }
        float yv = (y + uu * Dd) * SZ[row * 512 + d];
        u16 yh = bf16_rne(yv);
        Yh[row * 512 + d] = yh;
        Yl[row * 512 + d] = bf16_rne(yv - bf16_to_f(yh));
    }
}

// ---------------------------------------------------------------------------
extern "C" void kernel_launch(void* const* d_in, const int* in_sizes, int n_in,
                              void* d_out, int out_size, void* d_ws, size_t ws_size,
                              hipStream_t stream) {
    const float* h    = (const float*)d_in[0];
    const float* Wi_f = (const float*)d_in[1];
    const float* Wi_b = (const float*)d_in[2];
    const float* Wx_f = (const float*)d_in[3];
    const float* Wx_b = (const float*)d_in[4];
    const float* Wdt_f= (const float*)d_in[5];
    const float* Wdt_b= (const float*)d_in[6];
    const float* bdt_f= (const float*)d_in[7];
    const float* bdt_b= (const float*)d_in[8];
    const float* Al_f = (const float*)d_in[9];
    const float* Al_b = (const float*)d_in[10];
    const float* D_f  = (const float*)d_in[11];
    const float* D_b  = (const float*)d_in[12];
    const float* Wo   = (const float*)d_in[13];
    float* out = (float*)d_out;

    // ---- workspace layout --------------------------------------------------
    const size_t W_ELE = 1024 * 256;                 // Wi (per dir) / Wo elements
    const size_t FB   = (size_t)SEQLENc * D_INNERc;  // per-batch 512-wide
    const size_t FH   = (size_t)SEQLENc * D_MODELc;  // per-batch 256-wide
    const size_t FX   = (size_t)SEQLENc * 48;
    const size_t FP   = (size_t)NCHUNK * 16 * 512;

    const size_t fixed_bytes = 6 * W_ELE * sizeof(u16);
    const size_t per_b = 2 * FH * sizeof(u16)
                       + 2 * FB * sizeof(float)
                       + FX * sizeof(float)
                       + 2 * FP * sizeof(float)
                       + 2 * FB * sizeof(u16);
    int PB = 4;
    if (fixed_bytes + 4 * per_b + 8192 > ws_size) PB = 2;
    if (fixed_bytes + 2 * per_b + 8192 > ws_size) PB = 1;

    char* cur = (char*)d_ws;
    auto alloc = [&](size_t bytes) -> char* {
        char* p = cur; cur += (bytes + 255) & ~(size_t)255; return p;
    };
    u16* WiH[2]; u16* WiL[2];
    WiH[0] = (u16*)alloc(W_ELE * 2); WiL[0] = (u16*)alloc(W_ELE * 2);
    WiH[1] = (u16*)alloc(W_ELE * 2); WiL[1] = (u16*)alloc(W_ELE * 2);
    u16* WoH = (u16*)alloc(W_ELE * 2); u16* WoL = (u16*)alloc(W_ELE * 2);
    u16*   hH = (u16*)alloc((size_t)PB * FH * 2);
    u16*   hL = (u16*)alloc((size_t)PB * FH * 2);
    float* u  = (float*)alloc((size_t)PB * FB * 4);
    float* sz = (float*)alloc((size_t)PB * FB * 4);
    float* xd = (float*)alloc((size_t)PB * FX * 4);
    float* P  = (float*)alloc((size_t)PB * FP * 4);
    float* S  = (float*)alloc((size_t)PB * FP * 4);
    u16*   yH = (u16*)alloc((size_t)PB * FB * 2);
    u16*   yL = (u16*)alloc((size_t)PB * FB * 2);

    // ---- pre-split weights (once per call) --------------------------------
    {
        int n4 = (int)(W_ELE / 4);
        int blocks = (n4 + 255) / 256; if (blocks > 1024) blocks = 1024;
        split_kernel<<<blocks, 256, 0, stream>>>(Wi_f, WiH[0], WiL[0], n4);
        split_kernel<<<blocks, 256, 0, stream>>>(Wi_b, WiH[1], WiL[1], n4);
        split_kernel<<<blocks, 256, 0, stream>>>(Wo,   WoH,    WoL,    n4);
    }

    for (int b0 = 0; b0 < BATCHc; b0 += PB) {
        const int Mp = PB * SEQLENc;
        const float* hB = h   + (size_t)b0 * FH;
        float*       oB = out + (size_t)b0 * FH;

        {   // split h for this batch group (used by both dirs)
            int n4 = (int)((size_t)PB * FH / 4);
            int blocks = (n4 + 255) / 256; if (blocks > 2048) blocks = 2048;
            split_kernel<<<blocks, 256, 0, stream>>>(hB, hH, hL, n4);
        }

        for (int dir = 0; dir < 2; dir++) {
            const float* Wx  = dir ? Wx_b  : Wx_f;
            const float* Wdt = dir ? Wdt_b : Wdt_f;
            const float* bdt = dir ? bdt_b : bdt_f;
            const float* Al  = dir ? Al_b  : Al_f;
            const float* Dp  = dir ? D_b   : D_f;

            gemm_mfma<1><<<dim3(1024 / 128, Mp / 128), 256, 0, stream>>>(
                hH, hL, D_MODELc, WiH[dir], WiL[dir], D_MODELc,
                u, sz, Mp, 1024, D_MODELc);

            xdbl_kernel<<<Mp / 64, 256, 0, stream>>>(u, Wx, xd);

            scan_phaseA<<<dim3(NCHUNK, 2, PB), 256, 0, stream>>>(
                u, xd, Wdt, bdt, Al, P, S, dir);
            scan_phaseB<<<PB * 32, 256, 0, stream>>>(P, S);
            scan_phaseC<<<dim3(NCHUNK, 2, PB), 256, 0, stream>>>(
                u, xd, Wdt, bdt, Al, S, sz, Dp, yH, yL, dir);

            if (dir == 0)
                gemm_mfma<0><<<dim3(256 / 128, Mp / 128), 256, 0, stream>>>(
                    yH, yL, D_INNERc, WoH, WoL, 1024,
                    oB, nullptr, Mp, D_MODELc, D_INNERc);
            else
                gemm_mfma<2><<<dim3(256 / 128, Mp / 128), 256, 0, stream>>>(
                    yH, yL, D_INNERc, WoH + 512, WoL + 512, 1024,
                    oB, nullptr, Mp, D_MODELc, D_INNERc);
        }
    }
}

// Round 6
// 474.687 us; speedup vs baseline: 2.0719x; 1.0995x over previous
//
#include <hip/hip_runtime.h>
#include <hip/hip_bf16.h>
#include <cstddef>
#include <cstdint>

#define D_MODELc 256
#define D_STATEc 16
#define D_INNERc 512
#define DT_RANKc 16
#define BATCHc   4
#define SEQLENc  4096
#define NCHUNK   128
#define CHUNK    32                   // NCHUNK*CHUNK == SEQLEN

typedef unsigned short u16;
typedef __attribute__((ext_vector_type(8))) short bf16x8;   // 8 bf16 (4 VGPR)
typedef __attribute__((ext_vector_type(4))) float f32x4;    // 4 f32 acc

__device__ __forceinline__ float siluf(float v) { return v / (1.f + __expf(-v)); }

__device__ __forceinline__ u16 bf16_rne(float f) {
    uint32_t u = __float_as_uint(f);
    u += 0x7fffu + ((u >> 16) & 1u);
    return (u16)(u >> 16);
}
__device__ __forceinline__ float bf16_to_f(u16 h) {
    return __uint_as_float(((uint32_t)h) << 16);
}
// softplus, branchless, fast-math
__device__ __forceinline__ float softplusf(float x) {
    return fmaxf(x, 0.f) + __logf(1.f + __expf(-fabsf(x)));
}

// global->LDS direct copy, 16B per lane; LDS dest = wave-uniform base + lane*16
#define GLL16(g, l) __builtin_amdgcn_global_load_lds( \
    (const __attribute__((address_space(1))) uint32_t*)(g), \
    (__attribute__((address_space(3))) uint32_t*)(l), 16, 0, 0)

// ---------------------------------------------------------------------------
// split f32 -> (hi, lo) bf16 pair, vectorized x4
// ---------------------------------------------------------------------------
__global__ __launch_bounds__(256) void split_kernel(const float* __restrict__ in,
                                                    u16* __restrict__ hi,
                                                    u16* __restrict__ lo, int n4) {
    int i = blockIdx.x * 256 + threadIdx.x;
    const int stride = gridDim.x * 256;
    for (; i < n4; i += stride) {
        float4 v = ((const float4*)in)[i];
        u16 h0 = bf16_rne(v.x), h1 = bf16_rne(v.y), h2 = bf16_rne(v.z), h3 = bf16_rne(v.w);
        ushort4 hv; hv.x = h0; hv.y = h1; hv.z = h2; hv.w = h3;
        ushort4 lv;
        lv.x = bf16_rne(v.x - bf16_to_f(h0));
        lv.y = bf16_rne(v.y - bf16_to_f(h1));
        lv.z = bf16_rne(v.z - bf16_to_f(h2));
        lv.w = bf16_rne(v.w - bf16_to_f(h3));
        ((ushort4*)hi)[i] = hv;
        ((ushort4*)lo)[i] = lv;
    }
}

// ---------------------------------------------------------------------------
// Split-bf16 MFMA NT GEMM. Tile 128x128, BK=32, 4 waves.
// EPI==1 additionally emits split bf16 of silu(x) (uh/ul) for the xdbl GEMM.
// ---------------------------------------------------------------------------
template<int EPI>
__global__ __launch_bounds__(256) void gemm_mfma(
        const u16* __restrict__ Ah, const u16* __restrict__ Al, int lda,
        const u16* __restrict__ Bh, const u16* __restrict__ Bl, int ldb,
        float* __restrict__ out0, float* __restrict__ out1,
        u16* __restrict__ uh, u16* __restrict__ ul,
        int M, int N, int K) {
    __shared__ u16 lds[4][4][128][8];
    const int t    = threadIdx.x;
    const int lane = t & 63;
    const int wid  = t >> 6;
    const int wrow = wid >> 1, wcol = wid & 1;
    const int m0 = blockIdx.y * 128, n0 = blockIdx.x * 128;
    const int lr  = lane & 15;       // frag row/col within 16
    const int kgl = lane >> 4;       // k-group 0..3

    f32x4 acc[4][4] = {};

    for (int k0 = 0; k0 < K; k0 += 32) {
        #pragma unroll
        for (int i = 0; i < 8; i++) {
            int c    = i * 256 + t;          // chunk id
            int tile = c >> 9;               // 0..3
            int kg   = (c >> 7) & 3;
            int row  = c & 127;
            const u16* bsrc = (tile == 0) ? Ah : (tile == 1) ? Al : (tile == 2) ? Bh : Bl;
            int r0 = (tile < 2) ? m0 : n0;
            int ld = (tile < 2) ? lda : ldb;
            const u16* g = bsrc + (size_t)(r0 + row) * ld + k0 + kg * 8;
            GLL16(g, ((char*)lds) + (size_t)c * 16);
        }
        __syncthreads();

        bf16x8 afh[4], afl[4];
        #pragma unroll
        for (int mi = 0; mi < 4; mi++) {
            afh[mi] = *(const bf16x8*)&lds[0][kgl][wrow * 64 + mi * 16 + lr][0];
            afl[mi] = *(const bf16x8*)&lds[1][kgl][wrow * 64 + mi * 16 + lr][0];
        }
        #pragma unroll
        for (int ni = 0; ni < 4; ni++) {
            bf16x8 bfh = *(const bf16x8*)&lds[2][kgl][wcol * 64 + ni * 16 + lr][0];
            bf16x8 bfl = *(const bf16x8*)&lds[3][kgl][wcol * 64 + ni * 16 + lr][0];
            #pragma unroll
            for (int mi = 0; mi < 4; mi++) {
                acc[mi][ni] = __builtin_amdgcn_mfma_f32_16x16x32_bf16(afh[mi], bfh, acc[mi][ni], 0, 0, 0);
                acc[mi][ni] = __builtin_amdgcn_mfma_f32_16x16x32_bf16(afh[mi], bfl, acc[mi][ni], 0, 0, 0);
                acc[mi][ni] = __builtin_amdgcn_mfma_f32_16x16x32_bf16(afl[mi], bfh, acc[mi][ni], 0, 0, 0);
            }
        }
        __syncthreads();
    }

    // epilogue: C/D map col=lane&15, row=(lane>>4)*4+reg  [m89/m91]
    #pragma unroll
    for (int mi = 0; mi < 4; mi++) {
        #pragma unroll
        for (int ni = 0; ni < 4; ni++) {
            #pragma unroll
            for (int r = 0; r < 4; r++) {
                int m = m0 + wrow * 64 + mi * 16 + kgl * 4 + r;
                int n = n0 + wcol * 64 + ni * 16 + lr;
                float v = acc[mi][ni][r];
                if (EPI == 0) {
                    out0[(size_t)m * N + n] = v;
                } else if (EPI == 2) {
                    out0[(size_t)m * N + n] += v;
                } else {
                    float s = siluf(v);
                    if (n < 512) {
                        size_t idx = (size_t)m * 512 + n;
                        out0[idx] = s;
                        u16 sh = bf16_rne(s);
                        uh[idx] = sh;
                        ul[idx] = bf16_rne(s - bf16_to_f(sh));
                    } else {
                        out1[(size_t)m * 512 + (n - 512)] = s;
                    }
                }
            }
        }
    }
}

// ---------------------------------------------------------------------------
// xdbl MFMA GEMM: xd[m, 0..48) = sum_k u[m,k] * Wx[n,k], split-bf16.
// M-tile 64 (4 waves x one 16-row frag), N=48 (3 frags), BK=32, K=512.
// A (uh/ul) staged via global_load_lds; B (Wx hi/lo, 96KB) read from L2.
// ---------------------------------------------------------------------------
__global__ __launch_bounds__(256) void xdbl_mfma(
        const u16* __restrict__ Ah, const u16* __restrict__ Al,
        const u16* __restrict__ WxH, const u16* __restrict__ WxL,
        float* __restrict__ out) {
    __shared__ u16 lds[2][4][64][8];     // 8 KB
    const int t    = threadIdx.x;
    const int lane = t & 63;
    const int wid  = t >> 6;
    const int m0   = blockIdx.x * 64;
    const int lr   = lane & 15;
    const int kgl  = lane >> 4;

    f32x4 acc[3] = {};

    for (int k0 = 0; k0 < 512; k0 += 32) {
        #pragma unroll
        for (int i = 0; i < 2; i++) {
            int c    = i * 256 + t;          // 0..511
            int tile = c >> 8;               // 0..1 (Ah, Al)
            int kg   = (c >> 6) & 3;
            int row  = c & 63;
            const u16* bsrc = tile ? Al : Ah;
            const u16* g = bsrc + (size_t)(m0 + row) * 512 + k0 + kg * 8;
            GLL16(g, ((char*)lds) + (size_t)c * 16);
        }
        __syncthreads();

        bf16x8 afh = *(const bf16x8*)&lds[0][kgl][wid * 16 + lr][0];
        bf16x8 afl = *(const bf16x8*)&lds[1][kgl][wid * 16 + lr][0];
        #pragma unroll
        for (int nf = 0; nf < 3; nf++) {
            const size_t boff = (size_t)(nf * 16 + lr) * 512 + k0 + kgl * 8;
            bf16x8 bfh = *(const bf16x8*)(WxH + boff);
            bf16x8 bfl = *(const bf16x8*)(WxL + boff);
            acc[nf] = __builtin_amdgcn_mfma_f32_16x16x32_bf16(afh, bfh, acc[nf], 0, 0, 0);
            acc[nf] = __builtin_amdgcn_mfma_f32_16x16x32_bf16(afh, bfl, acc[nf], 0, 0, 0);
            acc[nf] = __builtin_amdgcn_mfma_f32_16x16x32_bf16(afl, bfh, acc[nf], 0, 0, 0);
        }
        __syncthreads();
    }

    #pragma unroll
    for (int nf = 0; nf < 3; nf++) {
        #pragma unroll
        for (int r = 0; r < 4; r++) {
            int m = m0 + wid * 16 + kgl * 4 + r;
            int n = nf * 16 + lr;
            out[(size_t)m * 48 + n] = acc[nf][r];
        }
    }
}

// ---------------------------------------------------------------------------
// Chunked scan. P/S layout: [b][chunk][n][d], d fastest.
// delta recomputed inline. dA via q-powers when a[n]==(n+1)*a0 (runtime check,
// generic exp fallback). Chunk decay p[n] = exp(a[n]*sum_dl) once per chunk.
// ---------------------------------------------------------------------------
__global__ __launch_bounds__(256) void scan_phaseA(
        const float* __restrict__ U, const float* __restrict__ XD,
        const float* __restrict__ Wdt, const float* __restrict__ bdt,
        const float* __restrict__ AL,
        float* __restrict__ P, float* __restrict__ S, int dir) {
    const int c = blockIdx.x;
    const int d = blockIdx.y * 256 + threadIdx.x;
    const int b = blockIdx.z;
    float w[16], a[16], s[16];
    #pragma unroll
    for (int n = 0; n < 16; n++) {
        w[n] = Wdt[d * 16 + n];
        a[n] = -__expf(AL[d * 16 + n]);
        s[n] = 0.f;
    }
    const float a0 = a[0];
    bool pw = (a0 != 0.f);
    #pragma unroll
    for (int n = 1; n < 16; n++)
        pw = pw && (fabsf(a[n] - (float)(n + 1) * a0) <= 3e-6f * fabsf(a[n]));
    const float bb = bdt[d];
    float sdl = 0.f;

    for (int i = 0; i < CHUNK; i++) {
        int tt = c * CHUNK + i;
        int l  = dir ? (SEQLENc - 1 - tt) : tt;
        size_t row = (size_t)b * SEQLENc + l;
        float uu = U[row * 512 + d];
        const float4* xr4 = (const float4*)&XD[row * 48];
        float acc = bb;
        #pragma unroll
        for (int k = 0; k < 4; k++) {
            float4 xa = xr4[k];
            acc += xa.x*w[k*4+0] + xa.y*w[k*4+1] + xa.z*w[k*4+2] + xa.w*w[k*4+3];
        }
        float dl = softplusf(acc);
        sdl += dl;
        float du = dl * uu;
        if (pw) {
            float q = __expf(a0 * dl);
            float dAn = 1.f;
            #pragma unroll
            for (int g = 0; g < 4; g++) {
                float4 B4 = xr4[4 + g];
                float bx[4] = {B4.x, B4.y, B4.z, B4.w};
                #pragma unroll
                for (int j = 0; j < 4; j++) {
                    int n = g * 4 + j;
                    dAn *= q;
                    s[n] = dAn * s[n] + du * bx[j];
                }
            }
        } else {
            #pragma unroll
            for (int g = 0; g < 4; g++) {
                float4 B4 = xr4[4 + g];
                float bx[4] = {B4.x, B4.y, B4.z, B4.w};
                #pragma unroll
                for (int j = 0; j < 4; j++) {
                    int n = g * 4 + j;
                    float dA = __expf(dl * a[n]);
                    s[n] = dA * s[n] + du * bx[j];
                }
            }
        }
    }
    size_t base = (((size_t)b * NCHUNK + c) * 16) * 512 + d;
    #pragma unroll
    for (int n = 0; n < 16; n++) {
        P[base + (size_t)n * 512] = __expf(a[n] * sdl);
        S[base + (size_t)n * 512] = s[n];
    }
}

// Serial over chunks with 1-deep prefetch; overwrites S with chunk ENTRY state.
__global__ __launch_bounds__(256) void scan_phaseB(const float* __restrict__ P,
                                                   float* __restrict__ S) {
    const int g = blockIdx.x * 256 + threadIdx.x;
    const int d = g & 511;
    const int n = (g >> 9) & 15;
    const int b = g >> 13;
    const size_t stride = (size_t)16 * 512;
    size_t off = (((size_t)b * NCHUNK) * 16 + n) * 512 + d;
    float carry = 0.f;
    float pp = P[off], ss = S[off];
    for (int c = 0; c < NCHUNK; c++) {
        float pn = 0.f, sn = 0.f;
        if (c + 1 < NCHUNK) { pn = P[off + stride]; sn = S[off + stride]; }
        S[off] = carry;
        carry = pp * carry + ss;
        pp = pn; ss = sn;
        off += stride;
    }
}

__global__ __launch_bounds__(256) void scan_phaseC(
        const float* __restrict__ U, const float* __restrict__ XD,
        const float* __restrict__ Wdt, const float* __restrict__ bdt,
        const float* __restrict__ AL,
        const float* __restrict__ E,    // entry states (in S buffer)
        const float* __restrict__ SZ,   // silu(z)
        const float* __restrict__ Dp,
        u16* __restrict__ Yh, u16* __restrict__ Yl, int dir) {
    const int c = blockIdx.x;
    const int d = blockIdx.y * 256 + threadIdx.x;
    const int b = blockIdx.z;
    float w[16], a[16], s[16];
    size_t base = (((size_t)b * NCHUNK + c) * 16) * 512 + d;
    #pragma unroll
    for (int n = 0; n < 16; n++) {
        w[n] = Wdt[d * 16 + n];
        a[n] = -__expf(AL[d * 16 + n]);
        s[n] = E[base + (size_t)n * 512];
    }
    const float a0 = a[0];
    bool pw = (a0 != 0.f);
    #pragma unroll
    for (int n = 1; n < 16; n++)
        pw = pw && (fabsf(a[n] - (float)(n + 1) * a0) <= 3e-6f * fabsf(a[n]));
    const float bb = bdt[d];
    const float Dd = Dp[d];

    for (int i = 0; i < CHUNK; i++) {
        int tt = c * CHUNK + i;
        int l  = dir ? (SEQLENc - 1 - tt) : tt;
        size_t row = (size_t)b * SEQLENc + l;
        float uu = U[row * 512 + d];
        const float4* xr4 = (const float4*)&XD[row * 48];
        float acc = bb;
        #pragma unroll
        for (int k = 0; k < 4; k++) {
            float4 xa = xr4[k];
            acc += xa.x*w[k*4+0] + xa.y*w[k*4+1] + xa.z*w[k*4+2] + xa.w*w[k*4+3];
        }
        float dl = softplusf(acc);
        float du = dl * uu;
        float y = 0.f;
        if (pw) {
            float q = __expf(a0 * dl);
            float dAn = 1.f;
            #pragma unroll
            for (int g = 0; g < 4; g++) {
                float4 B4 = xr4[4 + g];
                float4 C4 = xr4[8 + g];
                float bx[4] = {B4.x, B4.y, B4.z, B4.w};
                float cx[4] = {C4.x, C4.y, C4.z, C4.w};
                #pragma unroll
                for (int j = 0; j < 4; j++) {
                    int n = g * 4 + j;
                    dAn *= q;
                    s[n] = dAn * s[n] + du * bx[j];
                    y += s[n] * cx[j];
                }
            }
        } else {
            #pragma unroll
            for (int g = 0; g < 4; g++) {
                float4 B4 = xr4[4 + g];
                float4 C4 = xr4[8 + g];
                float bx[4] = {B4.x, B4.y, B4.z, B4.w};
                float cx[4] = {C4.x, C4.y, C4.z, C4.w};
                #pragma unroll
                for (int j = 0; j < 4; j++) {
                    int n = g * 4 + j;
                    float dA = __expf(dl * a[n]);
                    s[n] = dA * s[n] + du * bx[j];
                    y += s[n] * cx[j];
                }
            }
        }
        float yv = (y + uu * Dd) * SZ[row * 512 + d];
        u16 yh = bf16_rne(yv);
        Yh[row * 512 + d] = yh;
        Yl[row * 512 + d] = bf16_rne(yv - bf16_to_f(yh));
    }
}

// ---------------------------------------------------------------------------
extern "C" void kernel_launch(void* const* d_in, const int* in_sizes, int n_in,
                              void* d_out, int out_size, void* d_ws, size_t ws_size,
                              hipStream_t stream) {
    const float* h    = (const float*)d_in[0];
    const float* Wi_f = (const float*)d_in[1];
    const float* Wi_b = (const float*)d_in[2];
    const float* Wx_f = (const float*)d_in[3];
    const float* Wx_b = (const float*)d_in[4];
    const float* Wdt_f= (const float*)d_in[5];
    const float* Wdt_b= (const float*)d_in[6];
    const float* bdt_f= (const float*)d_in[7];
    const float* bdt_b= (const float*)d_in[8];
    const float* Al_f = (const float*)d_in[9];
    const float* Al_b = (const float*)d_in[10];
    const float* D_f  = (const float*)d_in[11];
    const float* D_b  = (const float*)d_in[12];
    const float* Wo   = (const float*)d_in[13];
    float* out = (float*)d_out;

    // ---- workspace layout --------------------------------------------------
    const size_t W_ELE = 1024 * 256;                 // Wi (per dir) / Wo elements
    const size_t WX_ELE = 48 * 512;                  // Wx per dir
    const size_t FB   = (size_t)SEQLENc * D_INNERc;  // per-batch 512-wide
    const size_t FH   = (size_t)SEQLENc * D_MODELc;  // per-batch 256-wide
    const size_t FX   = (size_t)SEQLENc * 48;
    const size_t FP   = (size_t)NCHUNK * 16 * 512;

    const size_t fixed_bytes = 6 * W_ELE * sizeof(u16) + 4 * WX_ELE * sizeof(u16);
    const size_t per_b = 2 * FH * sizeof(u16)                  // h hi/lo
                       + 2 * FB * sizeof(float)                // u, sz
                       + 2 * FB * sizeof(u16)                  // uh, ul
                       + FX * sizeof(float)                    // xd
                       + 2 * FP * sizeof(float)                // P, S
                       + 2 * FB * sizeof(u16);                 // y hi/lo
    int PB = 4;
    if (fixed_bytes + 4 * per_b + 16384 > ws_size) PB = 2;
    if (fixed_bytes + 2 * per_b + 16384 > ws_size) PB = 1;

    char* cur = (char*)d_ws;
    auto alloc = [&](size_t bytes) -> char* {
        char* p = cur; cur += (bytes + 255) & ~(size_t)255; return p;
    };
    u16* WiH[2]; u16* WiL[2]; u16* WxH[2]; u16* WxL[2];
    WiH[0] = (u16*)alloc(W_ELE * 2); WiL[0] = (u16*)alloc(W_ELE * 2);
    WiH[1] = (u16*)alloc(W_ELE * 2); WiL[1] = (u16*)alloc(W_ELE * 2);
    u16* WoH = (u16*)alloc(W_ELE * 2); u16* WoL = (u16*)alloc(W_ELE * 2);
    WxH[0] = (u16*)alloc(WX_ELE * 2); WxL[0] = (u16*)alloc(WX_ELE * 2);
    WxH[1] = (u16*)alloc(WX_ELE * 2); WxL[1] = (u16*)alloc(WX_ELE * 2);
    u16*   hH = (u16*)alloc((size_t)PB * FH * 2);
    u16*   hL = (u16*)alloc((size_t)PB * FH * 2);
    float* u  = (float*)alloc((size_t)PB * FB * 4);
    float* sz = (float*)alloc((size_t)PB * FB * 4);
    u16*   uhB= (u16*)alloc((size_t)PB * FB * 2);
    u16*   ulB= (u16*)alloc((size_t)PB * FB * 2);
    float* xd = (float*)alloc((size_t)PB * FX * 4);
    float* P  = (float*)alloc((size_t)PB * FP * 4);
    float* S  = (float*)alloc((size_t)PB * FP * 4);
    u16*   yH = (u16*)alloc((size_t)PB * FB * 2);
    u16*   yL = (u16*)alloc((size_t)PB * FB * 2);

    // ---- pre-split weights (once per call) --------------------------------
    {
        int n4 = (int)(W_ELE / 4);
        int blocks = (n4 + 255) / 256; if (blocks > 1024) blocks = 1024;
        split_kernel<<<blocks, 256, 0, stream>>>(Wi_f, WiH[0], WiL[0], n4);
        split_kernel<<<blocks, 256, 0, stream>>>(Wi_b, WiH[1], WiL[1], n4);
        split_kernel<<<blocks, 256, 0, stream>>>(Wo,   WoH,    WoL,    n4);
        int nx4 = (int)(WX_ELE / 4);
        split_kernel<<<(nx4 + 255) / 256, 256, 0, stream>>>(Wx_f, WxH[0], WxL[0], nx4);
        split_kernel<<<(nx4 + 255) / 256, 256, 0, stream>>>(Wx_b, WxH[1], WxL[1], nx4);
    }

    for (int b0 = 0; b0 < BATCHc; b0 += PB) {
        const int Mp = PB * SEQLENc;
        const float* hB = h   + (size_t)b0 * FH;
        float*       oB = out + (size_t)b0 * FH;

        {   // split h for this batch group (used by both dirs)
            int n4 = (int)((size_t)PB * FH / 4);
            int blocks = (n4 + 255) / 256; if (blocks > 2048) blocks = 2048;
            split_kernel<<<blocks, 256, 0, stream>>>(hB, hH, hL, n4);
        }

        for (int dir = 0; dir < 2; dir++) {
            const float* Wdt = dir ? Wdt_b : Wdt_f;
            const float* bdt = dir ? bdt_b : bdt_f;
            const float* Al  = dir ? Al_b  : Al_f;
            const float* Dp  = dir ? D_b   : D_f;

            gemm_mfma<1><<<dim3(1024 / 128, Mp / 128), 256, 0, stream>>>(
                hH, hL, D_MODELc, WiH[dir], WiL[dir], D_MODELc,
                u, sz, uhB, ulB, Mp, 1024, D_MODELc);

            xdbl_mfma<<<Mp / 64, 256, 0, stream>>>(uhB, ulB, WxH[dir], WxL[dir], xd);

            scan_phaseA<<<dim3(NCHUNK, 2, PB), 256, 0, stream>>>(
                u, xd, Wdt, bdt, Al, P, S, dir);
            scan_phaseB<<<PB * 32, 256, 0, stream>>>(P, S);
            scan_phaseC<<<dim3(NCHUNK, 2, PB), 256, 0, stream>>>(
                u, xd, Wdt, bdt, Al, S, sz, Dp, yH, yL, dir);

            if (dir == 0)
                gemm_mfma<0><<<dim3(256 / 128, Mp / 128), 256, 0, stream>>>(
                    yH, yL, D_INNERc, WoH, WoL, 1024,
                    oB, nullptr, nullptr, nullptr, Mp, D_MODELc, D_INNERc);
            else
                gemm_mfma<2><<<dim3(256 / 128, Mp / 128), 256, 0, stream>>>(
                    yH, yL, D_INNERc, WoH + 512, WoL + 512, 1024,
                    oB, nullptr, nullptr, nullptr, Mp, D_MODELc, D_INNERc);
        }
    }
}

// Round 7
// 427.318 us; speedup vs baseline: 2.3016x; 1.1109x over previous
//
#include <hip/hip_runtime.h>
#include <hip/hip_bf16.h>
#include <cstddef>
#include <cstdint>

#define D_MODELc 256
#define D_STATEc 16
#define D_INNERc 512
#define DT_RANKc 16
#define BATCHc   4
#define SEQLENc  4096
#define NCHUNK   128
#define CHUNK    32                   // NCHUNK*CHUNK == SEQLEN

typedef unsigned short u16;
typedef __attribute__((ext_vector_type(8))) short bf16x8;   // 8 bf16 (4 VGPR)
typedef __attribute__((ext_vector_type(4))) float f32x4;    // 4 f32 acc

__device__ __forceinline__ float siluf(float v) { return v / (1.f + __expf(-v)); }

__device__ __forceinline__ u16 bf16_rne(float f) {
    uint32_t u = __float_as_uint(f);
    u += 0x7fffu + ((u >> 16) & 1u);
    return (u16)(u >> 16);
}
__device__ __forceinline__ float bf16_to_f(u16 h) {
    return __uint_as_float(((uint32_t)h) << 16);
}
// softplus, branchless, fast-math
__device__ __forceinline__ float softplusf(float x) {
    return fmaxf(x, 0.f) + __logf(1.f + __expf(-fabsf(x)));
}

// global->LDS direct copy, 16B per lane; LDS dest = wave-uniform base + lane*16
#define GLL16(g, l) __builtin_amdgcn_global_load_lds( \
    (const __attribute__((address_space(1))) uint32_t*)(g), \
    (__attribute__((address_space(3))) uint32_t*)(l), 16, 0, 0)

// ---------------------------------------------------------------------------
// split f32 -> (hi, lo) bf16 pair, vectorized x4
// ---------------------------------------------------------------------------
__global__ __launch_bounds__(256) void split_kernel(const float* __restrict__ in,
                                                    u16* __restrict__ hi,
                                                    u16* __restrict__ lo, int n4) {
    int i = blockIdx.x * 256 + threadIdx.x;
    const int stride = gridDim.x * 256;
    for (; i < n4; i += stride) {
        float4 v = ((const float4*)in)[i];
        u16 h0 = bf16_rne(v.x), h1 = bf16_rne(v.y), h2 = bf16_rne(v.z), h3 = bf16_rne(v.w);
        ushort4 hv; hv.x = h0; hv.y = h1; hv.z = h2; hv.w = h3;
        ushort4 lv;
        lv.x = bf16_rne(v.x - bf16_to_f(h0));
        lv.y = bf16_rne(v.y - bf16_to_f(h1));
        lv.z = bf16_rne(v.z - bf16_to_f(h2));
        lv.w = bf16_rne(v.w - bf16_to_f(h3));
        ((ushort4*)hi)[i] = hv;
        ((ushort4*)lo)[i] = lv;
    }
}

// ---------------------------------------------------------------------------
// Split-bf16 MFMA NT GEMM. Tile 128x128, BK=32, 4 waves, 1-D grid of
// NB x (M/128) blocks with XCD-aware remap: consecutive dispatch ids
// round-robin XCDs; map id so each XCD owns a contiguous m-slice (its A
// panel then lives in its private L2) and all n-blocks of it.
// EPI==0: out0[m*N+n] = v                    (out-proj, N=256, NBL2=1)
// EPI==1: N==1024: n<512 -> uh/ul = split(silu(v)) ; else out0(sz)[m*512+n-512]
// ---------------------------------------------------------------------------
template<int EPI, int NBL2>
__global__ __launch_bounds__(256) void gemm_mfma(
        const u16* __restrict__ Ah, const u16* __restrict__ Al, int lda,
        const u16* __restrict__ Bh, const u16* __restrict__ Bl, int ldb,
        float* __restrict__ out0,
        u16* __restrict__ uh, u16* __restrict__ ul,
        int M, int N, int K) {
    __shared__ u16 lds[4][4][128][8];
    const int t    = threadIdx.x;
    const int lane = t & 63;
    const int wid  = t >> 6;
    const int wrow = wid >> 1, wcol = wid & 1;

    // XCD-aware bijective remap (blocks = NB * (M/128), M/128 % 8 == 0)
    const int id  = blockIdx.x;
    const int xcd = id & 7;
    const int j   = id >> 3;
    const int nb  = j & ((1 << NBL2) - 1);
    const int mg  = j >> NBL2;
    const int m0  = (mg * 8 + xcd) * 128;
    const int n0  = nb * 128;

    const int lr  = lane & 15;       // frag row/col within 16
    const int kgl = lane >> 4;       // k-group 0..3

    f32x4 acc[4][4] = {};

    for (int k0 = 0; k0 < K; k0 += 32) {
        #pragma unroll
        for (int i = 0; i < 8; i++) {
            int c    = i * 256 + t;          // chunk id
            int tile = c >> 9;               // 0..3
            int kg   = (c >> 7) & 3;
            int row  = c & 127;
            const u16* bsrc = (tile == 0) ? Ah : (tile == 1) ? Al : (tile == 2) ? Bh : Bl;
            int r0 = (tile < 2) ? m0 : n0;
            int ld = (tile < 2) ? lda : ldb;
            const u16* g = bsrc + (size_t)(r0 + row) * ld + k0 + kg * 8;
            GLL16(g, ((char*)lds) + (size_t)c * 16);
        }
        __syncthreads();

        bf16x8 afh[4], afl[4];
        #pragma unroll
        for (int mi = 0; mi < 4; mi++) {
            afh[mi] = *(const bf16x8*)&lds[0][kgl][wrow * 64 + mi * 16 + lr][0];
            afl[mi] = *(const bf16x8*)&lds[1][kgl][wrow * 64 + mi * 16 + lr][0];
        }
        #pragma unroll
        for (int ni = 0; ni < 4; ni++) {
            bf16x8 bfh = *(const bf16x8*)&lds[2][kgl][wcol * 64 + ni * 16 + lr][0];
            bf16x8 bfl = *(const bf16x8*)&lds[3][kgl][wcol * 64 + ni * 16 + lr][0];
            #pragma unroll
            for (int mi = 0; mi < 4; mi++) {
                acc[mi][ni] = __builtin_amdgcn_mfma_f32_16x16x32_bf16(afh[mi], bfh, acc[mi][ni], 0, 0, 0);
                acc[mi][ni] = __builtin_amdgcn_mfma_f32_16x16x32_bf16(afh[mi], bfl, acc[mi][ni], 0, 0, 0);
                acc[mi][ni] = __builtin_amdgcn_mfma_f32_16x16x32_bf16(afl[mi], bfh, acc[mi][ni], 0, 0, 0);
            }
        }
        __syncthreads();
    }

    // epilogue: C/D map col=lane&15, row=(lane>>4)*4+reg  [m89/m91]
    #pragma unroll
    for (int mi = 0; mi < 4; mi++) {
        #pragma unroll
        for (int ni = 0; ni < 4; ni++) {
            #pragma unroll
            for (int r = 0; r < 4; r++) {
                int m = m0 + wrow * 64 + mi * 16 + kgl * 4 + r;
                int n = n0 + wcol * 64 + ni * 16 + lr;
                float v = acc[mi][ni][r];
                if (EPI == 0) {
                    out0[(size_t)m * N + n] = v;
                } else {
                    float s = siluf(v);
                    if (n < 512) {
                        size_t idx = (size_t)m * 512 + n;
                        u16 sh = bf16_rne(s);
                        uh[idx] = sh;
                        ul[idx] = bf16_rne(s - bf16_to_f(sh));
                    } else {
                        out0[(size_t)m * 512 + (n - 512)] = s;   // sz
                    }
                }
            }
        }
    }
}

// ---------------------------------------------------------------------------
// xdbl MFMA GEMM: xd[m, 0..48) = sum_k u[m,k] * Wx[n,k], split-bf16.
// M-tile 64 (4 waves x one 16-row frag), N=48 (3 frags), BK=32, K=512.
// ---------------------------------------------------------------------------
__global__ __launch_bounds__(256) void xdbl_mfma(
        const u16* __restrict__ Ah, const u16* __restrict__ Al,
        const u16* __restrict__ WxH, const u16* __restrict__ WxL,
        float* __restrict__ out) {
    __shared__ u16 lds[2][4][64][8];     // 8 KB
    const int t    = threadIdx.x;
    const int lane = t & 63;
    const int wid  = t >> 6;
    const int m0   = blockIdx.x * 64;
    const int lr   = lane & 15;
    const int kgl  = lane >> 4;

    f32x4 acc[3] = {};

    for (int k0 = 0; k0 < 512; k0 += 32) {
        #pragma unroll
        for (int i = 0; i < 2; i++) {
            int c    = i * 256 + t;          // 0..511
            int tile = c >> 8;               // 0..1 (Ah, Al)
            int kg   = (c >> 6) & 3;
            int row  = c & 63;
            const u16* bsrc = tile ? Al : Ah;
            const u16* g = bsrc + (size_t)(m0 + row) * 512 + k0 + kg * 8;
            GLL16(g, ((char*)lds) + (size_t)c * 16);
        }
        __syncthreads();

        bf16x8 afh = *(const bf16x8*)&lds[0][kgl][wid * 16 + lr][0];
        bf16x8 afl = *(const bf16x8*)&lds[1][kgl][wid * 16 + lr][0];
        #pragma unroll
        for (int nf = 0; nf < 3; nf++) {
            const size_t boff = (size_t)(nf * 16 + lr) * 512 + k0 + kgl * 8;
            bf16x8 bfh = *(const bf16x8*)(WxH + boff);
            bf16x8 bfl = *(const bf16x8*)(WxL + boff);
            acc[nf] = __builtin_amdgcn_mfma_f32_16x16x32_bf16(afh, bfh, acc[nf], 0, 0, 0);
            acc[nf] = __builtin_amdgcn_mfma_f32_16x16x32_bf16(afh, bfl, acc[nf], 0, 0, 0);
            acc[nf] = __builtin_amdgcn_mfma_f32_16x16x32_bf16(afl, bfh, acc[nf], 0, 0, 0);
        }
        __syncthreads();
    }

    #pragma unroll
    for (int nf = 0; nf < 3; nf++) {
        #pragma unroll
        for (int r = 0; r < 4; r++) {
            int m = m0 + wid * 16 + kgl * 4 + r;
            int n = nf * 16 + lr;
            out[(size_t)m * 48 + n] = acc[nf][r];
        }
    }
}

// ---------------------------------------------------------------------------
// Chunked scan. P/S layout: [b][chunk][n][d], d fastest.
// u reconstructed from split bf16 (uh+ul). delta recomputed inline.
// dA via q-powers when a[n]==(n+1)*a0 (runtime check, generic fallback).
// ---------------------------------------------------------------------------
__global__ __launch_bounds__(256) void scan_phaseA(
        const u16* __restrict__ Uh, const u16* __restrict__ Ul,
        const float* __restrict__ XD,
        const float* __restrict__ Wdt, const float* __restrict__ bdt,
        const float* __restrict__ AL,
        float* __restrict__ P, float* __restrict__ S, int dir) {
    const int c = blockIdx.x;
    const int d = blockIdx.y * 256 + threadIdx.x;
    const int b = blockIdx.z;
    float w[16], a[16], s[16];
    #pragma unroll
    for (int n = 0; n < 16; n++) {
        w[n] = Wdt[d * 16 + n];
        a[n] = -__expf(AL[d * 16 + n]);
        s[n] = 0.f;
    }
    const float a0 = a[0];
    bool pw = (a0 != 0.f);
    #pragma unroll
    for (int n = 1; n < 16; n++)
        pw = pw && (fabsf(a[n] - (float)(n + 1) * a0) <= 3e-6f * fabsf(a[n]));
    const float bb = bdt[d];
    float sdl = 0.f;

    for (int i = 0; i < CHUNK; i++) {
        int tt = c * CHUNK + i;
        int l  = dir ? (SEQLENc - 1 - tt) : tt;
        size_t row = (size_t)b * SEQLENc + l;
        float uu = bf16_to_f(Uh[row * 512 + d]) + bf16_to_f(Ul[row * 512 + d]);
        const float4* xr4 = (const float4*)&XD[row * 48];
        float acc = bb;
        #pragma unroll
        for (int k = 0; k < 4; k++) {
            float4 xa = xr4[k];
            acc += xa.x*w[k*4+0] + xa.y*w[k*4+1] + xa.z*w[k*4+2] + xa.w*w[k*4+3];
        }
        float dl = softplusf(acc);
        sdl += dl;
        float du = dl * uu;
        if (pw) {
            float q = __expf(a0 * dl);
            float dAn = 1.f;
            #pragma unroll
            for (int g = 0; g < 4; g++) {
                float4 B4 = xr4[4 + g];
                float bx[4] = {B4.x, B4.y, B4.z, B4.w};
                #pragma unroll
                for (int j = 0; j < 4; j++) {
                    int n = g * 4 + j;
                    dAn *= q;
                    s[n] = dAn * s[n] + du * bx[j];
                }
            }
        } else {
            #pragma unroll
            for (int g = 0; g < 4; g++) {
                float4 B4 = xr4[4 + g];
                float bx[4] = {B4.x, B4.y, B4.z, B4.w};
                #pragma unroll
                for (int j = 0; j < 4; j++) {
                    int n = g * 4 + j;
                    float dA = __expf(dl * a[n]);
                    s[n] = dA * s[n] + du * bx[j];
                }
            }
        }
    }
    size_t base = (((size_t)b * NCHUNK + c) * 16) * 512 + d;
    #pragma unroll
    for (int n = 0; n < 16; n++) {
        P[base + (size_t)n * 512] = __expf(a[n] * sdl);
        S[base + (size_t)n * 512] = s[n];
    }
}

// Serial over chunks with 1-deep prefetch; overwrites S with chunk ENTRY state.
__global__ __launch_bounds__(256) void scan_phaseB(const float* __restrict__ P,
                                                   float* __restrict__ S) {
    const int g = blockIdx.x * 256 + threadIdx.x;
    const int d = g & 511;
    const int n = (g >> 9) & 15;
    const int b = g >> 13;
    const size_t stride = (size_t)16 * 512;
    size_t off = (((size_t)b * NCHUNK) * 16 + n) * 512 + d;
    float carry = 0.f;
    float pp = P[off], ss = S[off];
    for (int c = 0; c < NCHUNK; c++) {
        float pn = 0.f, sn = 0.f;
        if (c + 1 < NCHUNK) { pn = P[off + stride]; sn = S[off + stride]; }
        S[off] = carry;
        carry = pp * carry + ss;
        pp = pn; ss = sn;
        off += stride;
    }
}

__global__ __launch_bounds__(256) void scan_phaseC(
        const u16* __restrict__ Uh, const u16* __restrict__ Ul,
        const float* __restrict__ XD,
        const float* __restrict__ Wdt, const float* __restrict__ bdt,
        const float* __restrict__ AL,
        const float* __restrict__ E,    // entry states (in S buffer)
        const float* __restrict__ SZ,   // silu(z)
        const float* __restrict__ Dp,
        u16* __restrict__ Yh, u16* __restrict__ Yl, int dir) {
    const int c = blockIdx.x;
    const int d = blockIdx.y * 256 + threadIdx.x;
    const int b = blockIdx.z;
    float w[16], a[16], s[16];
    size_t base = (((size_t)b * NCHUNK + c) * 16) * 512 + d;
    #pragma unroll
    for (int n = 0; n < 16; n++) {
        w[n] = Wdt[d * 16 + n];
        a[n] = -__expf(AL[d * 16 + n]);
        s[n] = E[base + (size_t)n * 512];
    }
    const float a0 = a[0];
    bool pw = (a0 != 0.f);
    #pragma unroll
    for (int n = 1; n < 16; n++)
        pw = pw && (fabsf(a[n] - (float)(n + 1) * a0) <= 3e-6f * fabsf(a[n]));
    const float bb = bdt[d];
    const float Dd = Dp[d];

    for (int i = 0; i < CHUNK; i++) {
        int tt = c * CHUNK + i;
        int l  = dir ? (SEQLENc - 1 - tt) : tt;
        size_t row = (size_t)b * SEQLENc + l;
        float uu = bf16_to_f(Uh[row * 512 + d]) + bf16_to_f(Ul[row * 512 + d]);
        const float4* xr4 = (const float4*)&XD[row * 48];
        float acc = bb;
        #pragma unroll
        for (int k = 0; k < 4; k++) {
            float4 xa = xr4[k];
            acc += xa.x*w[k*4+0] + xa.y*w[k*4+1] + xa.z*w[k*4+2] + xa.w*w[k*4+3];
        }
        float dl = softplusf(acc);
        float du = dl * uu;
        float y = 0.f;
        if (pw) {
            float q = __expf(a0 * dl);
            float dAn = 1.f;
            #pragma unroll
            for (int g = 0; g < 4; g++) {
                float4 B4 = xr4[4 + g];
                float4 C4 = xr4[8 + g];
                float bx[4] = {B4.x, B4.y, B4.z, B4.w};
                float cx[4] = {C4.x, C4.y, C4.z, C4.w};
                #pragma unroll
                for (int j = 0; j < 4; j++) {
                    int n = g * 4 + j;
                    dAn *= q;
                    s[n] = dAn * s[n] + du * bx[j];
                    y += s[n] * cx[j];
                }
            }
        } else {
            #pragma unroll
            for (int g = 0; g < 4; g++) {
                float4 B4 = xr4[4 + g];
                float4 C4 = xr4[8 + g];
                float bx[4] = {B4.x, B4.y, B4.z, B4.w};
                float cx[4] = {C4.x, C4.y, C4.z, C4.w};
                #pragma unroll
                for (int j = 0; j < 4; j++) {
                    int n = g * 4 + j;
                    float dA = __expf(dl * a[n]);
                    s[n] = dA * s[n] + du * bx[j];
                    y += s[n] * cx[j];
                }
            }
        }
        float yv = (y + uu * Dd) * SZ[row * 512 + d];
        size_t yi = row * 1024 + (size_t)dir * 512 + d;   // dir-concatenated
        u16 yh = bf16_rne(yv);
        Yh[yi] = yh;
        Yl[yi] = bf16_rne(yv - bf16_to_f(yh));
    }
}

// ---------------------------------------------------------------------------
extern "C" void kernel_launch(void* const* d_in, const int* in_sizes, int n_in,
                              void* d_out, int out_size, void* d_ws, size_t ws_size,
                              hipStream_t stream) {
    const float* h    = (const float*)d_in[0];
    const float* Wi_f = (const float*)d_in[1];
    const float* Wi_b = (const float*)d_in[2];
    const float* Wx_f = (const float*)d_in[3];
    const float* Wx_b = (const float*)d_in[4];
    const float* Wdt_f= (const float*)d_in[5];
    const float* Wdt_b= (const float*)d_in[6];
    const float* bdt_f= (const float*)d_in[7];
    const float* bdt_b= (const float*)d_in[8];
    const float* Al_f = (const float*)d_in[9];
    const float* Al_b = (const float*)d_in[10];
    const float* D_f  = (const float*)d_in[11];
    const float* D_b  = (const float*)d_in[12];
    const float* Wo   = (const float*)d_in[13];
    float* out = (float*)d_out;

    // ---- workspace layout --------------------------------------------------
    const size_t W_ELE  = 1024 * 256;                 // Wi (per dir) / Wo elements
    const size_t WX_ELE = 48 * 512;                   // Wx per dir
    const size_t FB   = (size_t)SEQLENc * D_INNERc;   // per-batch 512-wide
    const size_t FH   = (size_t)SEQLENc * D_MODELc;   // per-batch 256-wide
    const size_t FX   = (size_t)SEQLENc * 48;
    const size_t FP   = (size_t)NCHUNK * 16 * 512;
    const size_t FY   = (size_t)SEQLENc * 1024;       // dir-concatenated y

    const size_t fixed_bytes = 6 * W_ELE * sizeof(u16) + 4 * WX_ELE * sizeof(u16);
    const size_t per_b = 2 * FH * sizeof(u16)                  // h hi/lo
                       + FB * sizeof(float)                    // sz
                       + 2 * FB * sizeof(u16)                  // uh, ul
                       + FX * sizeof(float)                    // xd
                       + 2 * FP * sizeof(float)                // P, S
                       + 2 * FY * sizeof(u16);                 // y hi/lo (1024-wide)
    int PB = 4;
    if (fixed_bytes + 4 * per_b + 16384 > ws_size) PB = 2;
    if (fixed_bytes + 2 * per_b + 16384 > ws_size) PB = 1;

    char* cur = (char*)d_ws;
    auto alloc = [&](size_t bytes) -> char* {
        char* p = cur; cur += (bytes + 255) & ~(size_t)255; return p;
    };
    u16* WiH[2]; u16* WiL[2]; u16* WxH[2]; u16* WxL[2];
    WiH[0] = (u16*)alloc(W_ELE * 2); WiL[0] = (u16*)alloc(W_ELE * 2);
    WiH[1] = (u16*)alloc(W_ELE * 2); WiL[1] = (u16*)alloc(W_ELE * 2);
    u16* WoH = (u16*)alloc(W_ELE * 2); u16* WoL = (u16*)alloc(W_ELE * 2);
    WxH[0] = (u16*)alloc(WX_ELE * 2); WxL[0] = (u16*)alloc(WX_ELE * 2);
    WxH[1] = (u16*)alloc(WX_ELE * 2); WxL[1] = (u16*)alloc(WX_ELE * 2);
    u16*   hH = (u16*)alloc((size_t)PB * FH * 2);
    u16*   hL = (u16*)alloc((size_t)PB * FH * 2);
    float* sz = (float*)alloc((size_t)PB * FB * 4);
    u16*   uhB= (u16*)alloc((size_t)PB * FB * 2);
    u16*   ulB= (u16*)alloc((size_t)PB * FB * 2);
    float* xd = (float*)alloc((size_t)PB * FX * 4);
    float* P  = (float*)alloc((size_t)PB * FP * 4);
    float* S  = (float*)alloc((size_t)PB * FP * 4);
    u16*   yH = (u16*)alloc((size_t)PB * FY * 2);
    u16*   yL = (u16*)alloc((size_t)PB * FY * 2);

    // ---- pre-split weights (once per call) --------------------------------
    {
        int n4 = (int)(W_ELE / 4);
        int blocks = (n4 + 255) / 256; if (blocks > 1024) blocks = 1024;
        split_kernel<<<blocks, 256, 0, stream>>>(Wi_f, WiH[0], WiL[0], n4);
        split_kernel<<<blocks, 256, 0, stream>>>(Wi_b, WiH[1], WiL[1], n4);
        split_kernel<<<blocks, 256, 0, stream>>>(Wo,   WoH,    WoL,    n4);
        int nx4 = (int)(WX_ELE / 4);
        split_kernel<<<(nx4 + 255) / 256, 256, 0, stream>>>(Wx_f, WxH[0], WxL[0], nx4);
        split_kernel<<<(nx4 + 255) / 256, 256, 0, stream>>>(Wx_b, WxH[1], WxL[1], nx4);
    }

    for (int b0 = 0; b0 < BATCHc; b0 += PB) {
        const int Mp = PB * SEQLENc;
        const int MB = Mp / 128;                     // multiple of 8 for all PB
        const float* hB = h   + (size_t)b0 * FH;
        float*       oB = out + (size_t)b0 * FH;

        {   // split h for this batch group (used by both dirs)
            int n4 = (int)((size_t)PB * FH / 4);
            int blocks = (n4 + 255) / 256; if (blocks > 2048) blocks = 2048;
            split_kernel<<<blocks, 256, 0, stream>>>(hB, hH, hL, n4);
        }

        for (int dir = 0; dir < 2; dir++) {
            const float* Wdt = dir ? Wdt_b : Wdt_f;
            const float* bdt = dir ? bdt_b : bdt_f;
            const float* Al  = dir ? Al_b  : Al_f;
            const float* Dp  = dir ? D_b   : D_f;

            // in-projection: N=1024 (NB=8, NBL2=3), emits uh/ul + sz
            gemm_mfma<1, 3><<<8 * MB, 256, 0, stream>>>(
                hH, hL, D_MODELc, WiH[dir], WiL[dir], D_MODELc,
                sz, uhB, ulB, Mp, 1024, D_MODELc);

            xdbl_mfma<<<Mp / 64, 256, 0, stream>>>(uhB, ulB, WxH[dir], WxL[dir], xd);

            scan_phaseA<<<dim3(NCHUNK, 2, PB), 256, 0, stream>>>(
                uhB, ulB, xd, Wdt, bdt, Al, P, S, dir);
            scan_phaseB<<<PB * 32, 256, 0, stream>>>(P, S);
            scan_phaseC<<<dim3(NCHUNK, 2, PB), 256, 0, stream>>>(
                uhB, ulB, xd, Wdt, bdt, Al, S, sz, Dp, yH, yL, dir);
        }

        // single fused out-projection over dir-concatenated y: K=1024, N=256
        gemm_mfma<0, 1><<<2 * MB, 256, 0, stream>>>(
            yH, yL, 1024, WoH, WoL, 1024,
            oB, nullptr, nullptr, Mp, D_MODELc, 1024);
    }
}

// Round 8
// 371.636 us; speedup vs baseline: 2.6464x; 1.1498x over previous
//
#include <hip/hip_runtime.h>
#include <hip/hip_bf16.h>
#include <cstddef>
#include <cstdint>

#define D_MODELc 256
#define D_STATEc 16
#define D_INNERc 512
#define DT_RANKc 16
#define BATCHc   4
#define SEQLENc  4096
#define NCHUNK   128
#define CHUNK    32                   // NCHUNK*CHUNK == SEQLEN

typedef unsigned short u16;
typedef __attribute__((ext_vector_type(8))) short bf16x8;   // 8 bf16 (4 VGPR)
typedef __attribute__((ext_vector_type(4))) float f32x4;    // 4 f32 acc

__device__ __forceinline__ float siluf(float v) { return v / (1.f + __expf(-v)); }

__device__ __forceinline__ u16 bf16_rne(float f) {
    uint32_t u = __float_as_uint(f);
    u += 0x7fffu + ((u >> 16) & 1u);
    return (u16)(u >> 16);
}
__device__ __forceinline__ float bf16_to_f(u16 h) {
    return __uint_as_float(((uint32_t)h) << 16);
}
// softplus, branchless, fast-math
__device__ __forceinline__ float softplusf(float x) {
    return fmaxf(x, 0.f) + __logf(1.f + __expf(-fabsf(x)));
}

// global->LDS direct copy, 16B per lane; LDS dest = wave-uniform base + lane*16
#define GLL16(g, l) __builtin_amdgcn_global_load_lds( \
    (const __attribute__((address_space(1))) uint32_t*)(g), \
    (__attribute__((address_space(3))) uint32_t*)(l), 16, 0, 0)

// ---------------------------------------------------------------------------
// split f32 -> (hi, lo) bf16 pair, vectorized x4
// ---------------------------------------------------------------------------
__global__ __launch_bounds__(256) void split_kernel(const float* __restrict__ in,
                                                    u16* __restrict__ hi,
                                                    u16* __restrict__ lo, int n4) {
    int i = blockIdx.x * 256 + threadIdx.x;
    const int stride = gridDim.x * 256;
    for (; i < n4; i += stride) {
        float4 v = ((const float4*)in)[i];
        u16 h0 = bf16_rne(v.x), h1 = bf16_rne(v.y), h2 = bf16_rne(v.z), h3 = bf16_rne(v.w);
        ushort4 hv; hv.x = h0; hv.y = h1; hv.z = h2; hv.w = h3;
        ushort4 lv;
        lv.x = bf16_rne(v.x - bf16_to_f(h0));
        lv.y = bf16_rne(v.y - bf16_to_f(h1));
        lv.z = bf16_rne(v.z - bf16_to_f(h2));
        lv.w = bf16_rne(v.w - bf16_to_f(h3));
        ((ushort4*)hi)[i] = hv;
        ((ushort4*)lo)[i] = lv;
    }
}

// ---------------------------------------------------------------------------
// Split-bf16 MFMA NT GEMM, 2-phase double-buffered (T3-minimal):
// prologue stages tile 0; each iteration issues global_load_lds for tile k+1,
// then ds_reads+MFMAs tile k, then ONE barrier. Tile 128x128, BK=32, 4 waves,
// LDS 2 x 32KB. XCD-aware bijective block remap (id&7 = XCD).
// EPI==0: out0[m*N+n] = v   (out-proj, N=256)
// EPI==1: merged in-proj, N==2048: dir=n>>10, nn=n&1023;
//         nn<512 -> uh/ul[dir*M*512 + m*512+nn] = split(silu(v))
//         else   -> sz [dir*M*512 + m*512+nn-512] = silu(v)
// ---------------------------------------------------------------------------
template<int EPI, int NBL2>
__global__ __launch_bounds__(256) void gemm_mfma(
        const u16* __restrict__ Ah, const u16* __restrict__ Al, int lda,
        const u16* __restrict__ Bh, const u16* __restrict__ Bl, int ldb,
        float* __restrict__ out0,
        u16* __restrict__ uh, u16* __restrict__ ul,
        int M, int N, int K) {
    __shared__ u16 lds[2][4][4][128][8];   // [buf][tile][kg][row][8] = 64 KB
    const int t    = threadIdx.x;
    const int lane = t & 63;
    const int wid  = t >> 6;
    const int wrow = wid >> 1, wcol = wid & 1;

    // XCD-aware bijective remap (blocks = NB * (M/128), M/128 % 8 == 0)
    const int id  = blockIdx.x;
    const int xcd = id & 7;
    const int j   = id >> 3;
    const int nb  = j & ((1 << NBL2) - 1);
    const int mg  = j >> NBL2;
    const int m0  = (mg * 8 + xcd) * 128;
    const int n0  = nb * 128;

    const int lr  = lane & 15;       // frag row/col within 16
    const int kgl = lane >> 4;       // k-group 0..3

    f32x4 acc[4][4] = {};

    auto stage = [&](int buf, int k0) {
        #pragma unroll
        for (int i = 0; i < 8; i++) {
            int c    = i * 256 + t;          // chunk id 0..2047
            int tile = c >> 9;               // 0..3
            int kg   = (c >> 7) & 3;
            int row  = c & 127;
            const u16* bsrc = (tile == 0) ? Ah : (tile == 1) ? Al : (tile == 2) ? Bh : Bl;
            int r0 = (tile < 2) ? m0 : n0;
            int ld = (tile < 2) ? lda : ldb;
            const u16* g = bsrc + (size_t)(r0 + row) * ld + k0 + kg * 8;
            GLL16(g, ((char*)lds) + (size_t)buf * 32768 + (size_t)c * 16);
        }
    };

    const int NT = K >> 5;
    stage(0, 0);
    __syncthreads();

    for (int kt = 0; kt < NT; ++kt) {
        const int buf = kt & 1;
        if (kt + 1 < NT) stage(buf ^ 1, (kt + 1) * 32);

        bf16x8 afh[4], afl[4];
        #pragma unroll
        for (int mi = 0; mi < 4; mi++) {
            afh[mi] = *(const bf16x8*)&lds[buf][0][kgl][wrow * 64 + mi * 16 + lr][0];
            afl[mi] = *(const bf16x8*)&lds[buf][1][kgl][wrow * 64 + mi * 16 + lr][0];
        }
        #pragma unroll
        for (int ni = 0; ni < 4; ni++) {
            bf16x8 bfh = *(const bf16x8*)&lds[buf][2][kgl][wcol * 64 + ni * 16 + lr][0];
            bf16x8 bfl = *(const bf16x8*)&lds[buf][3][kgl][wcol * 64 + ni * 16 + lr][0];
            #pragma unroll
            for (int mi = 0; mi < 4; mi++) {
                acc[mi][ni] = __builtin_amdgcn_mfma_f32_16x16x32_bf16(afh[mi], bfh, acc[mi][ni], 0, 0, 0);
                acc[mi][ni] = __builtin_amdgcn_mfma_f32_16x16x32_bf16(afh[mi], bfl, acc[mi][ni], 0, 0, 0);
                acc[mi][ni] = __builtin_amdgcn_mfma_f32_16x16x32_bf16(afl[mi], bfh, acc[mi][ni], 0, 0, 0);
            }
        }
        __syncthreads();   // drains prefetch vmcnt + protects buf reuse
    }

    // epilogue: C/D map col=lane&15, row=(lane>>4)*4+reg  [m89/m91]
    #pragma unroll
    for (int mi = 0; mi < 4; mi++) {
        #pragma unroll
        for (int ni = 0; ni < 4; ni++) {
            #pragma unroll
            for (int r = 0; r < 4; r++) {
                int m = m0 + wrow * 64 + mi * 16 + kgl * 4 + r;
                int n = n0 + wcol * 64 + ni * 16 + lr;
                float v = acc[mi][ni][r];
                if (EPI == 0) {
                    out0[(size_t)m * N + n] = v;
                } else {
                    float s = siluf(v);
                    int dirn = n >> 10;
                    int nn   = n & 1023;
                    size_t dof = (size_t)dirn * (size_t)M * 512;
                    if (nn < 512) {
                        size_t idx = dof + (size_t)m * 512 + nn;
                        u16 sh = bf16_rne(s);
                        uh[idx] = sh;
                        ul[idx] = bf16_rne(s - bf16_to_f(sh));
                    } else {
                        out0[dof + (size_t)m * 512 + (nn - 512)] = s;   // sz
                    }
                }
            }
        }
    }
}

// ---------------------------------------------------------------------------
// xdbl MFMA GEMM, both dirs (blockIdx.y): xd[m,0..48) = sum_k u[m,k]*Wx[n,k].
// M-tile 64 (4 waves x one 16-row frag), N=48 (3 frags), BK=32, K=512.
// ---------------------------------------------------------------------------
__global__ __launch_bounds__(256) void xdbl_mfma(
        const u16* __restrict__ Uh, const u16* __restrict__ Ul,
        const u16* __restrict__ WxH, const u16* __restrict__ WxL,
        float* __restrict__ out) {
    __shared__ u16 lds[2][4][64][8];     // 8 KB
    const int t    = threadIdx.x;
    const int lane = t & 63;
    const int wid  = t >> 6;
    const int m0   = blockIdx.x * 64;
    const int dir  = blockIdx.y;
    const int Mp   = gridDim.x * 64;
    const int lr   = lane & 15;
    const int kgl  = lane >> 4;

    const size_t dofU = (size_t)dir * (size_t)Mp * 512;
    const size_t dofW = (size_t)dir * (size_t)48 * 512;
    const u16* Ah = Uh + dofU;
    const u16* Al = Ul + dofU;

    f32x4 acc[3] = {};

    for (int k0 = 0; k0 < 512; k0 += 32) {
        #pragma unroll
        for (int i = 0; i < 2; i++) {
            int c    = i * 256 + t;          // 0..511
            int tile = c >> 8;               // 0..1 (Ah, Al)
            int kg   = (c >> 6) & 3;
            int row  = c & 63;
            const u16* bsrc = tile ? Al : Ah;
            const u16* g = bsrc + (size_t)(m0 + row) * 512 + k0 + kg * 8;
            GLL16(g, ((char*)lds) + (size_t)c * 16);
        }
        __syncthreads();

        bf16x8 afh = *(const bf16x8*)&lds[0][kgl][wid * 16 + lr][0];
        bf16x8 afl = *(const bf16x8*)&lds[1][kgl][wid * 16 + lr][0];
        #pragma unroll
        for (int nf = 0; nf < 3; nf++) {
            const size_t boff = dofW + (size_t)(nf * 16 + lr) * 512 + k0 + kgl * 8;
            bf16x8 bfh = *(const bf16x8*)(WxH + boff);
            bf16x8 bfl = *(const bf16x8*)(WxL + boff);
            acc[nf] = __builtin_amdgcn_mfma_f32_16x16x32_bf16(afh, bfh, acc[nf], 0, 0, 0);
            acc[nf] = __builtin_amdgcn_mfma_f32_16x16x32_bf16(afh, bfl, acc[nf], 0, 0, 0);
            acc[nf] = __builtin_amdgcn_mfma_f32_16x16x32_bf16(afl, bfh, acc[nf], 0, 0, 0);
        }
        __syncthreads();
    }

    float* o = out + (size_t)dir * (size_t)Mp * 48;
    #pragma unroll
    for (int nf = 0; nf < 3; nf++) {
        #pragma unroll
        for (int r = 0; r < 4; r++) {
            int m = m0 + wid * 16 + kgl * 4 + r;
            int n = nf * 16 + lr;
            o[(size_t)m * 48 + n] = acc[nf][r];
        }
    }
}

// ---------------------------------------------------------------------------
// Chunked scan, both dirs merged (z = b*2 + dir).
// S layout: [z][chunk][n][d]; SDL: [z][chunk][d] (sum of delta per chunk).
// u from split bf16 (uh+ul); delta recomputed inline; dA via q-powers when
// a[n]==(n+1)*a0 (runtime check, generic exp fallback).
// ---------------------------------------------------------------------------
__global__ __launch_bounds__(256) void scan_phaseA(
        const u16* __restrict__ Uh, const u16* __restrict__ Ul,
        const float* __restrict__ XD,
        const float* __restrict__ Wdt_f, const float* __restrict__ Wdt_b,
        const float* __restrict__ bdt_f, const float* __restrict__ bdt_b,
        const float* __restrict__ AL_f, const float* __restrict__ AL_b,
        float* __restrict__ SDL, float* __restrict__ S) {
    const int c   = blockIdx.x;
    const int d   = blockIdx.y * 256 + threadIdx.x;
    const int z   = blockIdx.z;
    const int dir = z & 1;
    const int b   = z >> 1;
    const int PB  = gridDim.z >> 1;
    const int Mp  = PB * SEQLENc;
    const float* Wdt = dir ? Wdt_b : Wdt_f;
    const float* bdt = dir ? bdt_b : bdt_f;
    const float* AL  = dir ? AL_b  : AL_f;
    const u16* UhD = Uh + (size_t)dir * Mp * 512;
    const u16* UlD = Ul + (size_t)dir * Mp * 512;
    const float* XDD = XD + (size_t)dir * Mp * 48;

    float w[16], a[16], s[16];
    #pragma unroll
    for (int n = 0; n < 16; n++) {
        w[n] = Wdt[d * 16 + n];
        a[n] = -__expf(AL[d * 16 + n]);
        s[n] = 0.f;
    }
    const float a0 = a[0];
    bool pw = (a0 != 0.f);
    #pragma unroll
    for (int n = 1; n < 16; n++)
        pw = pw && (fabsf(a[n] - (float)(n + 1) * a0) <= 3e-6f * fabsf(a[n]));
    const float bb = bdt[d];
    float sdl = 0.f;

    for (int i = 0; i < CHUNK; i++) {
        int tt = c * CHUNK + i;
        int l  = dir ? (SEQLENc - 1 - tt) : tt;
        size_t row = (size_t)b * SEQLENc + l;
        float uu = bf16_to_f(UhD[row * 512 + d]) + bf16_to_f(UlD[row * 512 + d]);
        const float4* xr4 = (const float4*)&XDD[row * 48];
        float acc = bb;
        #pragma unroll
        for (int k = 0; k < 4; k++) {
            float4 xa = xr4[k];
            acc += xa.x*w[k*4+0] + xa.y*w[k*4+1] + xa.z*w[k*4+2] + xa.w*w[k*4+3];
        }
        float dl = softplusf(acc);
        sdl += dl;
        float du = dl * uu;
        if (pw) {
            float q = __expf(a0 * dl);
            float dAn = 1.f;
            #pragma unroll
            for (int g = 0; g < 4; g++) {
                float4 B4 = xr4[4 + g];
                float bx[4] = {B4.x, B4.y, B4.z, B4.w};
                #pragma unroll
                for (int jj = 0; jj < 4; jj++) {
                    int n = g * 4 + jj;
                    dAn *= q;
                    s[n] = dAn * s[n] + du * bx[jj];
                }
            }
        } else {
            #pragma unroll
            for (int g = 0; g < 4; g++) {
                float4 B4 = xr4[4 + g];
                float bx[4] = {B4.x, B4.y, B4.z, B4.w};
                #pragma unroll
                for (int jj = 0; jj < 4; jj++) {
                    int n = g * 4 + jj;
                    float dA = __expf(dl * a[n]);
                    s[n] = dA * s[n] + du * bx[jj];
                }
            }
        }
    }
    SDL[((size_t)z * NCHUNK + c) * 512 + d] = sdl;
    size_t base = (((size_t)z * NCHUNK + c) * 16) * 512 + d;
    #pragma unroll
    for (int n = 0; n < 16; n++)
        S[base + (size_t)n * 512] = s[n];
}

// Serial over chunks; P recomputed from SDL (p = exp(a_n * sdl)).
// Overwrites S with the chunk ENTRY state.
__global__ __launch_bounds__(256) void scan_phaseB(const float* __restrict__ SDL,
                                                   float* __restrict__ S,
                                                   const float* __restrict__ AL_f,
                                                   const float* __restrict__ AL_b) {
    const int g   = blockIdx.x * 256 + threadIdx.x;
    const int d   = g & 511;
    const int n   = (g >> 9) & 15;
    const int z   = g >> 13;
    const int dir = z & 1;
    const float an = -__expf((dir ? AL_b : AL_f)[d * 16 + n]);
    const size_t strideS = (size_t)16 * 512;
    size_t offS = (((size_t)z * NCHUNK) * 16 + n) * 512 + d;
    size_t offD = ((size_t)z * NCHUNK) * 512 + d;
    float carry = 0.f;
    float sdl = SDL[offD], ss = S[offS];
    for (int c = 0; c < NCHUNK; c++) {
        float sdn = 0.f, sn = 0.f;
        if (c + 1 < NCHUNK) { sdn = SDL[offD + 512]; sn = S[offS + strideS]; }
        float pp = __expf(an * sdl);
        S[offS] = carry;               // entry state for chunk c
        carry = pp * carry + ss;
        sdl = sdn; ss = sn;
        offS += strideS; offD += 512;
    }
}

__global__ __launch_bounds__(256) void scan_phaseC(
        const u16* __restrict__ Uh, const u16* __restrict__ Ul,
        const float* __restrict__ XD,
        const float* __restrict__ Wdt_f, const float* __restrict__ Wdt_b,
        const float* __restrict__ bdt_f, const float* __restrict__ bdt_b,
        const float* __restrict__ AL_f, const float* __restrict__ AL_b,
        const float* __restrict__ E,    // entry states (in S buffer)
        const float* __restrict__ SZ,   // silu(z), dir-strided
        const float* __restrict__ D_f,  const float* __restrict__ D_b,
        u16* __restrict__ Yh, u16* __restrict__ Yl) {
    const int c   = blockIdx.x;
    const int d   = blockIdx.y * 256 + threadIdx.x;
    const int z   = blockIdx.z;
    const int dir = z & 1;
    const int b   = z >> 1;
    const int PB  = gridDim.z >> 1;
    const int Mp  = PB * SEQLENc;
    const float* Wdt = dir ? Wdt_b : Wdt_f;
    const float* bdt = dir ? bdt_b : bdt_f;
    const float* AL  = dir ? AL_b  : AL_f;
    const u16* UhD = Uh + (size_t)dir * Mp * 512;
    const u16* UlD = Ul + (size_t)dir * Mp * 512;
    const float* XDD = XD + (size_t)dir * Mp * 48;
    const float* SZD = SZ + (size_t)dir * Mp * 512;

    float w[16], a[16], s[16];
    size_t base = (((size_t)z * NCHUNK + c) * 16) * 512 + d;
    #pragma unroll
    for (int n = 0; n < 16; n++) {
        w[n] = Wdt[d * 16 + n];
        a[n] = -__expf(AL[d * 16 + n]);
        s[n] = E[base + (size_t)n * 512];
    }
    const float a0 = a[0];
    bool pw = (a0 != 0.f);
    #pragma unroll
    for (int n = 1; n < 16; n++)
        pw = pw && (fabsf(a[n] - (float)(n + 1) * a0) <= 3e-6f * fabsf(a[n]));
    const float bb = bdt[d];
    const float Dd = (dir ? D_b : D_f)[d];

    for (int i = 0; i < CHUNK; i++) {
        int tt = c * CHUNK + i;
        int l  = dir ? (SEQLENc - 1 - tt) : tt;
        size_t row = (size_t)b * SEQLENc + l;
        float uu = bf16_to_f(UhD[row * 512 + d]) + bf16_to_f(UlD[row * 512 + d]);
        const float4* xr4 = (const float4*)&XDD[row * 48];
        float acc = bb;
        #pragma unroll
        for (int k = 0; k < 4; k++) {
            float4 xa = xr4[k];
            acc += xa.x*w[k*4+0] + xa.y*w[k*4+1] + xa.z*w[k*4+2] + xa.w*w[k*4+3];
        }
        float dl = softplusf(acc);
        float du = dl * uu;
        float y = 0.f;
        if (pw) {
            float q = __expf(a0 * dl);
            float dAn = 1.f;
            #pragma unroll
            for (int g = 0; g < 4; g++) {
                float4 B4 = xr4[4 + g];
                float4 C4 = xr4[8 + g];
                float bx[4] = {B4.x, B4.y, B4.z, B4.w};
                float cx[4] = {C4.x, C4.y, C4.z, C4.w};
                #pragma unroll
                for (int jj = 0; jj < 4; jj++) {
                    int n = g * 4 + jj;
                    dAn *= q;
                    s[n] = dAn * s[n] + du * bx[jj];
                    y += s[n] * cx[jj];
                }
            }
        } else {
            #pragma unroll
            for (int g = 0; g < 4; g++) {
                float4 B4 = xr4[4 + g];
                float4 C4 = xr4[8 + g];
                float bx[4] = {B4.x, B4.y, B4.z, B4.w};
                float cx[4] = {C4.x, C4.y, C4.z, C4.w};
                #pragma unroll
                for (int jj = 0; jj < 4; jj++) {
                    int n = g * 4 + jj;
                    float dA = __expf(dl * a[n]);
                    s[n] = dA * s[n] + du * bx[jj];
                    y += s[n] * cx[jj];
                }
            }
        }
        float yv = (y + uu * Dd) * SZD[row * 512 + d];
        size_t yi = row * 1024 + (size_t)dir * 512 + d;   // dir-concatenated
        u16 yh = bf16_rne(yv);
        Yh[yi] = yh;
        Yl[yi] = bf16_rne(yv - bf16_to_f(yh));
    }
}

// ---------------------------------------------------------------------------
extern "C" void kernel_launch(void* const* d_in, const int* in_sizes, int n_in,
                              void* d_out, int out_size, void* d_ws, size_t ws_size,
                              hipStream_t stream) {
    const float* h    = (const float*)d_in[0];
    const float* Wi_f = (const float*)d_in[1];
    const float* Wi_b = (const float*)d_in[2];
    const float* Wx_f = (const float*)d_in[3];
    const float* Wx_b = (const float*)d_in[4];
    const float* Wdt_f= (const float*)d_in[5];
    const float* Wdt_b= (const float*)d_in[6];
    const float* bdt_f= (const float*)d_in[7];
    const float* bdt_b= (const float*)d_in[8];
    const float* Al_f = (const float*)d_in[9];
    const float* Al_b = (const float*)d_in[10];
    const float* D_f  = (const float*)d_in[11];
    const float* D_b  = (const float*)d_in[12];
    const float* Wo   = (const float*)d_in[13];
    float* out = (float*)d_out;

    // ---- workspace layout --------------------------------------------------
    const size_t W_ELE  = 1024 * 256;                 // Wi per dir / Wo elements
    const size_t WX_ELE = 48 * 512;                   // Wx per dir
    const size_t FB   = (size_t)SEQLENc * D_INNERc;   // per-batch 512-wide
    const size_t FH   = (size_t)SEQLENc * D_MODELc;   // per-batch 256-wide
    const size_t FX   = (size_t)SEQLENc * 48;
    const size_t FP   = (size_t)NCHUNK * 16 * 512;    // S per batch-dir
    const size_t FD   = (size_t)NCHUNK * 512;         // SDL per batch-dir
    const size_t FY   = (size_t)SEQLENc * 1024;       // dir-concat y

    const size_t fixed_bytes = (8 * W_ELE + 4 * WX_ELE) * sizeof(u16);
    const size_t per_b = 2 * FH * sizeof(u16)                  // h hi/lo
                       + 2 * FB * sizeof(float)                // sz (2 dirs)
                       + 4 * FB * sizeof(u16)                  // uh/ul (2 dirs)
                       + 2 * FX * sizeof(float)                // xd (2 dirs)
                       + 2 * (FP + FD) * sizeof(float)         // S + SDL (2 dirs)
                       + 2 * FY * sizeof(u16);                 // y hi/lo
    int PB = 4;
    if (fixed_bytes + 4 * per_b + 65536 > ws_size) PB = 2;
    if (fixed_bytes + 2 * per_b + 65536 > ws_size) PB = 1;

    char* cur = (char*)d_ws;
    auto alloc = [&](size_t bytes) -> char* {
        char* p = cur; cur += (bytes + 255) & ~(size_t)255; return p;
    };
    u16* WiH = (u16*)alloc(2 * W_ELE * 2);   // both dirs concatenated (2048x256)
    u16* WiL = (u16*)alloc(2 * W_ELE * 2);
    u16* WoH = (u16*)alloc(W_ELE * 2);
    u16* WoL = (u16*)alloc(W_ELE * 2);
    u16* WxH = (u16*)alloc(2 * WX_ELE * 2);  // both dirs concatenated
    u16* WxL = (u16*)alloc(2 * WX_ELE * 2);
    u16*   hH = (u16*)alloc((size_t)PB * FH * 2);
    u16*   hL = (u16*)alloc((size_t)PB * FH * 2);
    float* sz = (float*)alloc((size_t)PB * 2 * FB * 4);
    u16*   uhB= (u16*)alloc((size_t)PB * 2 * FB * 2);
    u16*   ulB= (u16*)alloc((size_t)PB * 2 * FB * 2);
    float* xd = (float*)alloc((size_t)PB * 2 * FX * 4);
    float* SDL= (float*)alloc((size_t)PB * 2 * FD * 4);
    float* S  = (float*)alloc((size_t)PB * 2 * FP * 4);
    u16*   yH = (u16*)alloc((size_t)PB * FY * 2);
    u16*   yL = (u16*)alloc((size_t)PB * FY * 2);

    // ---- pre-split weights (once per call) --------------------------------
    {
        int n4 = (int)(W_ELE / 4);
        int blocks = (n4 + 255) / 256; if (blocks > 1024) blocks = 1024;
        split_kernel<<<blocks, 256, 0, stream>>>(Wi_f, WiH, WiL, n4);
        split_kernel<<<blocks, 256, 0, stream>>>(Wi_b, WiH + W_ELE, WiL + W_ELE, n4);
        split_kernel<<<blocks, 256, 0, stream>>>(Wo,   WoH, WoL, n4);
        int nx4 = (int)(WX_ELE / 4);
        split_kernel<<<(nx4 + 255) / 256, 256, 0, stream>>>(Wx_f, WxH, WxL, nx4);
        split_kernel<<<(nx4 + 255) / 256, 256, 0, stream>>>(Wx_b, WxH + WX_ELE, WxL + WX_ELE, nx4);
    }

    for (int b0 = 0; b0 < BATCHc; b0 += PB) {
        const int Mp = PB * SEQLENc;
        const int MB = Mp / 128;                     // multiple of 8 for all PB
        const float* hB = h   + (size_t)b0 * FH;
        float*       oB = out + (size_t)b0 * FH;

        {   // split h for this batch group
            int n4 = (int)((size_t)PB * FH / 4);
            int blocks = (n4 + 255) / 256; if (blocks > 2048) blocks = 2048;
            split_kernel<<<blocks, 256, 0, stream>>>(hB, hH, hL, n4);
        }

        // merged in-projection for BOTH dirs: N=2048 (NB=16, NBL2=4)
        gemm_mfma<1, 4><<<16 * MB, 256, 0, stream>>>(
            hH, hL, D_MODELc, WiH, WiL, D_MODELc,
            sz, uhB, ulB, Mp, 2048, D_MODELc);

        // xdbl for both dirs
        xdbl_mfma<<<dim3(Mp / 64, 2), 256, 0, stream>>>(uhB, ulB, WxH, WxL, xd);

        // scans, both dirs merged (z = b*2 + dir)
        scan_phaseA<<<dim3(NCHUNK, 2, 2 * PB), 256, 0, stream>>>(
            uhB, ulB, xd, Wdt_f, Wdt_b, bdt_f, bdt_b, Al_f, Al_b, SDL, S);
        scan_phaseB<<<PB * 64, 256, 0, stream>>>(SDL, S, Al_f, Al_b);
        scan_phaseC<<<dim3(NCHUNK, 2, 2 * PB), 256, 0, stream>>>(
            uhB, ulB, xd, Wdt_f, Wdt_b, bdt_f, bdt_b, Al_f, Al_b,
            S, sz, D_f, D_b, yH, yL);

        // single fused out-projection: K=1024, N=256 (NB=2, NBL2=1)
        gemm_mfma<0, 1><<<2 * MB, 256, 0, stream>>>(
            yH, yL, 1024, WoH, WoL, 1024,
            oB, nullptr, nullptr, Mp, D_MODELc, 1024);
    }
}